// Round 8
// baseline (1838.777 us; speedup 1.0000x reference)
//
#include <hip/hip_runtime.h>
#include <cstdio>

typedef __bf16 bf16x8 __attribute__((ext_vector_type(8)));
typedef float f32x4 __attribute__((ext_vector_type(4)));
typedef int i32x4 __attribute__((ext_vector_type(4)));
typedef unsigned short u16x4 __attribute__((ext_vector_type(4)));

__device__ __forceinline__ float bf2f(unsigned short u) {
  union { unsigned int i; float f; } x; x.i = ((unsigned int)u) << 16; return x.f;
}
__device__ __forceinline__ unsigned short f2bf(float f) {
  union { float f; unsigned int i; } x; x.f = f;
  unsigned int r = x.i + 0x7fffu + ((x.i >> 16) & 1u);
  return (unsigned short)(r >> 16);
}

// async global->LDS, 16B per lane; LDS dest is wave-uniform base + lane*16
__device__ __forceinline__ void gl2lds16(const unsigned short* g, unsigned short* l) {
  __builtin_amdgcn_global_load_lds((const __attribute__((address_space(1))) unsigned int*)g,
                                   (__attribute__((address_space(3))) unsigned int*)l, 16, 0, 0);
}

// ---------------- elementwise f32 -> bf16 cast (vec4) ----------------
__global__ __launch_bounds__(256) void k_cast(const float* __restrict__ in,
                                              unsigned short* __restrict__ out, int n4) {
  int i = blockIdx.x * 256 + threadIdx.x;
  if (i >= n4) return;
  f32x4 v = ((const f32x4*)in)[i];
  u16x4 o;
  o[0] = f2bf(v[0]); o[1] = f2bf(v[1]); o[2] = f2bf(v[2]); o[3] = f2bf(v[3]);
  ((u16x4*)out)[i] = o;
}

// -------- transpose-cast: src f32 [K][N] -> dst bf16 [N][K] --------
__global__ __launch_bounds__(256) void k_tcast(const float* __restrict__ src,
                                               unsigned short* __restrict__ dst,
                                               int K, int N) {
  __shared__ float tile[32][33];
  int gx = blockIdx.x * 32;  // N dim
  int gy = blockIdx.y * 32;  // K dim
  int t = threadIdx.x;
  int c = t & 31, r0 = t >> 5;
#pragma unroll
  for (int i = 0; i < 4; i++) {
    int r = r0 + i * 8;
    tile[r][c] = src[(size_t)(gy + r) * N + gx + c];
  }
  __syncthreads();
#pragma unroll
  for (int i = 0; i < 4; i++) {
    int r = r0 + i * 8;
    dst[(size_t)(gx + r) * K + gy + c] = f2bf(tile[c][r]);
  }
}

// ---- folded bias: out[n] = bv[n] + sum_j bk[j]*wv[j][n]  (f32, 1024 wide) ----
__global__ __launch_bounds__(256) void k_bfold(const float* __restrict__ bk,
                                               const float* __restrict__ wv,
                                               const float* __restrict__ bv,
                                               float* __restrict__ out) {
  int n = blockIdx.x * 256 + threadIdx.x;
  float acc = bv[n];
#pragma unroll 8
  for (int j = 0; j < 1024; j++) acc += bk[j] * wv[(size_t)j * 1024 + n];
  out[n] = acc;
}

// ---- concat two 1024-f32 vectors into out[0..2047] ----
__global__ __launch_bounds__(256) void k_cpb(const float* __restrict__ a,
                                             const float* __restrict__ b,
                                             float* __restrict__ out) {
  int t = blockIdx.x * 256 + threadIdx.x;
  out[t] = a[t];
  out[1024 + t] = b[t];
}

// ======== MFMA GEMM: 128x128 tile, BK=32, ring-3 LDS, counted vmcnt, vectorized epilogue ========
// C[M][N] = A[M][K](bf16 rm) * Bt[N][K]^T + bias (opt exact GELU); bias may be null (=0).
// 256 threads = 4 waves (2x2), wave tile 64x64 via 4x4 mfma 16x16x32.
template <bool GELU>
__global__ __launch_bounds__(256) void k_gemm(const unsigned short* __restrict__ A,
                                              const unsigned short* __restrict__ Bt,
                                              const float* __restrict__ bias,
                                              unsigned short* __restrict__ C,
                                              int M, int N, int K) {
  __shared__ unsigned short As[3][128 * 32];
  __shared__ unsigned short Bs[3][128 * 32];
  const int rowA0 = blockIdx.y * 128, colB0 = blockIdx.x * 128;
  const int t = threadIdx.x, w = t >> 6, lane = t & 63;
  const int wr = w >> 1, wc = w & 1;
  const int srow = w * 16 + (lane >> 2);
  const int schunk = (lane & 3) ^ ((lane >> 3) & 3);  // granule ^ ((row>>1)&3)
  const unsigned short* pa = A + (size_t)(rowA0 + srow) * K + schunk * 8;
  const unsigned short* pb = Bt + (size_t)(colB0 + srow) * K + schunk * 8;
  const size_t row64 = (size_t)64 * K;

  f32x4 acc[4][4] = {};
  const int g = lane >> 4, ra = lane & 15;
  const int gp8 = (g ^ ((ra >> 1) & 3)) * 8;  // read-side inverse swizzle

  auto stage = [&](int buf, int kk) {
    gl2lds16(pa + kk,         &As[buf][w * 512]);
    gl2lds16(pa + row64 + kk, &As[buf][2048 + w * 512]);
    gl2lds16(pb + kk,         &Bs[buf][w * 512]);
    gl2lds16(pb + row64 + kk, &Bs[buf][2048 + w * 512]);
  };

  const int NT = K >> 5;
  stage(0, 0);
  if (NT > 1) stage(1, 32);
  int cur = 0;
  for (int j = 0; j < NT; ++j) {
    if (j + 2 < NT) {
      int nxt2 = cur + 2; if (nxt2 >= 3) nxt2 -= 3;
      stage(nxt2, (j + 2) * 32);
      asm volatile("s_waitcnt vmcnt(8)" ::: "memory");   // tile j arrived; j+1, j+2 in flight
    } else if (j + 1 < NT) {
      asm volatile("s_waitcnt vmcnt(4)" ::: "memory");
    } else {
      asm volatile("s_waitcnt vmcnt(0)" ::: "memory");
    }
    __syncthreads();
    bf16x8 af[4], bfr[4];
#pragma unroll
    for (int m = 0; m < 4; m++)
      af[m] = *(const bf16x8*)&As[cur][(wr * 64 + m * 16 + ra) * 32 + gp8];
#pragma unroll
    for (int n = 0; n < 4; n++)
      bfr[n] = *(const bf16x8*)&Bs[cur][(wc * 64 + n * 16 + ra) * 32 + gp8];
#pragma unroll
    for (int m = 0; m < 4; m++)
#pragma unroll
      for (int n = 0; n < 4; n++)
        acc[m][n] = __builtin_amdgcn_mfma_f32_16x16x32_bf16(af[m], bfr[n], acc[m][n], 0, 0, 0);
    __syncthreads();   // all reads of buf cur done before it is restaged (at iter j+1)
    cur += 1; if (cur >= 3) cur -= 3;
  }

  // ---- epilogue: per-wave LDS transpose (XOR-swizzled), 16B coalesced stores ----
  unsigned short* Ep = &As[0][0] + w * 1024;  // 16x64 u16 region per wave (loop fully drained)
  const int grow0 = rowA0 + wr * 64;
  const int gcol0 = colB0 + wc * 64;
  float bv[4];
#pragma unroll
  for (int n = 0; n < 4; n++) bv[n] = bias ? bias[gcol0 + n * 16 + ra] : 0.f;
  const int rdrow = lane >> 3, rg = lane & 7;
#pragma unroll
  for (int m = 0; m < 4; m++) {
#pragma unroll
    for (int n = 0; n < 4; n++)
#pragma unroll
      for (int i = 0; i < 4; i++) {
        int r = g * 4 + i;
        float v = acc[m][n][i] + bv[n];
        if (GELU) v = 0.5f * v * (1.f + erff(v * 0.70710678118654752f));
        Ep[r * 64 + ((ra + n * 16) ^ ((r & 7) << 3))] = f2bf(v);
      }
    asm volatile("s_waitcnt lgkmcnt(0)" ::: "memory");  // wave-local: writes visible to all lanes
    __builtin_amdgcn_sched_barrier(0);
#pragma unroll
    for (int p = 0; p < 2; p++) {
      int rr = p * 8 + rdrow;
      bf16x8 val = *(const bf16x8*)&Ep[rr * 64 + ((rg ^ (rr & 7)) << 3)];
      *(bf16x8*)&C[(size_t)(grow0 + m * 16 + rr) * N + gcol0 + rg * 8] = val;
    }
    asm volatile("s_waitcnt lgkmcnt(0)" ::: "memory");  // reads done before next slice overwrites
  }
}

// ---------------- small GEMM (M<=10): C[Mr][1024] = A[Mr][1024] * Wt^T + bias ----------------
__global__ __launch_bounds__(256) void k_gemm10(const unsigned short* __restrict__ A,
                                                const unsigned short* __restrict__ Bt,
                                                const float* __restrict__ bias,
                                                unsigned short* __restrict__ C) {
  __shared__ float af[1024];
  int m = blockIdx.x, nb = blockIdx.y;
  int t = threadIdx.x;
#pragma unroll
  for (int i = 0; i < 4; i++) af[t * 4 + i] = bf2f(A[(size_t)m * 1024 + t * 4 + i]);
  __syncthreads();
  int w = t >> 6, lane = t & 63;
  for (int n = nb * 64 + w; n < nb * 64 + 64; n += 4) {
    const unsigned short* brow = Bt + (size_t)n * 1024 + lane * 16;
    float acc = 0.f;
#pragma unroll
    for (int j = 0; j < 16; j++) acc += af[lane * 16 + j] * bf2f(brow[j]);
#pragma unroll
    for (int o = 32; o; o >>= 1) acc += __shfl_xor(acc, o);
    if (lane == 0) C[(size_t)m * 1024 + n] = f2bf(acc + bias[n]);
  }
}

// ---------------- entmax-1.5 attention, MFMA version (RS = input row stride) ----------------
// Output in torch Hopfield "mix" layout: out[batch][h*(L/16)+l/16][(l%16)*64+e], stride 1024.
template <int L, int S, bool SHARED>
__global__ __launch_bounds__(256) void k_attn(const unsigned short* __restrict__ Q,
                                              const unsigned short* __restrict__ Kb,
                                              const unsigned short* __restrict__ Vb,
                                              unsigned short* __restrict__ Out, int RS) {
  constexpr int SP = (S <= 32) ? 32 : 64;  // S padded to MFMA K-multiple
  constexpr int QST = 72;                  // Q/K row stride (bf16), pad for bank spread
  constexpr int VST = SP + 8;              // Vt/P row stride
  constexpr int CST = SP + 4;              // scores row stride (f32)
  __shared__ unsigned short Qs[L * QST];   // reused as P (stride VST) in phase 3
  __shared__ unsigned short Ks[SP * QST];
  __shared__ unsigned short Vt[64 * VST];  // Vt[e][s] = V[s][e]
  __shared__ float Sc[L * CST];
  __shared__ float Rps[L];
  const int blk = blockIdx.x, batch = blk >> 4, h = blk & 15;
  const int t = threadIdx.x, w = t >> 6, lane = t & 63;

  // --- stage Q (16B chunks) ---
  for (int c = t; c < L * 8; c += 256) {
    int r = c >> 3, ch = (c & 7) * 8;
    *(i32x4*)&Qs[r * QST + ch] =
        *(const i32x4*)&Q[((size_t)(batch * L + r)) * RS + h * 64 + ch];
  }
  // --- stage K rows (zero rows >= S) ---
  for (int c = t; c < SP * 8; c += 256) {
    int r = c >> 3, ch = (c & 7) * 8;
    i32x4 v = {0, 0, 0, 0};
    if (r < S) {
      size_t rb = SHARED ? (size_t)r : (size_t)(batch * S + r);
      v = *(const i32x4*)&Kb[rb * RS + h * 64 + ch];
    }
    *(i32x4*)&Ks[r * QST + ch] = v;
  }
  // --- stage V transposed (zero cols >= S) ---
  for (int c = t; c < SP * 64; c += 256) {
    int s = c >> 6, e = c & 63;
    unsigned short v = 0;
    if (s < S) {
      size_t rb = SHARED ? (size_t)s : (size_t)(batch * S + s);
      v = Vb[rb * RS + h * 64 + e];
    }
    Vt[e * VST + s] = v;
  }
  __syncthreads();

  const int ka = (lane >> 4) * 8, ra = lane & 15;
  const int cr = (lane >> 4) * 4, cc = lane & 15;
  // --- phase 1: scores = (Q K^T) * 0.5/sqrt(64) ---
  constexpr int NT = SP / 16, TT = (L / 16) * NT;
  for (int tt = w; tt < TT; tt += 4) {
    int m = tt / NT, n = tt % NT;
    f32x4 a = {0.f, 0.f, 0.f, 0.f};
#pragma unroll
    for (int ks = 0; ks < 2; ks++) {  // E=64 -> 2 K-steps
      bf16x8 af = *(const bf16x8*)&Qs[(m * 16 + ra) * QST + ks * 32 + ka];
      bf16x8 bf = *(const bf16x8*)&Ks[(n * 16 + ra) * QST + ks * 32 + ka];
      a = __builtin_amdgcn_mfma_f32_16x16x32_bf16(af, bf, a, 0, 0, 0);
    }
#pragma unroll
    for (int i = 0; i < 4; i++)
      Sc[(m * 16 + cr + i) * CST + n * 16 + cc] = a[i] * 0.0625f;
  }
  __syncthreads();

  // --- phase 2: bisection, G lanes per row, scores in registers ---
  constexpr int G = 256 / L, RW = 64 / G, SL = SP / G;
  const int row = w * RW + lane / G, sub = lane % G;
  float xs[SL];
#pragma unroll
  for (int j = 0; j < SL; j++) {
    int s = sub * SL + j;
    float v = Sc[row * CST + s];
    if (S < SP && s >= S) v = -1e30f;
    xs[j] = v;
  }
  float mx = xs[0];
#pragma unroll
  for (int j = 1; j < SL; j++) mx = fmaxf(mx, xs[j]);
#pragma unroll
  for (int o = G / 2; o; o >>= 1) mx = fmaxf(mx, __shfl_xor(mx, o));
  const float hoff = (S == 64) ? 0.125f : (S == 32) ? 0.17677669529663687f : 0.31622776601683794f;
  float lo = mx - 1.f, hi = mx - hoff;
#pragma unroll 1
  for (int it = 0; it < 26; it++) {
    float mid = 0.5f * (lo + hi);
    float f = 0.f;
#pragma unroll
    for (int j = 0; j < SL; j++) { float dd = fmaxf(xs[j] - mid, 0.f); f += dd * dd; }
#pragma unroll
    for (int o = G / 2; o; o >>= 1) f += __shfl_xor(f, o);
    bool gt = f > 1.f;
    lo = gt ? mid : lo;
    hi = gt ? hi : mid;
  }
  float tau = 0.5f * (lo + hi);
  float ps = 0.f;
#pragma unroll
  for (int j = 0; j < SL; j++) { float dd = fmaxf(xs[j] - tau, 0.f); xs[j] = dd * dd; ps += xs[j]; }
#pragma unroll
  for (int o = G / 2; o; o >>= 1) ps += __shfl_xor(ps, o);
  if (sub == 0) Rps[row] = 1.f / ps;
  unsigned short* Pb = Qs;  // reuse Qs as P (unnormalized, bf16, stride VST)
#pragma unroll
  for (int j = 0; j < SL; j += 4) {
    u16x4 pv;
#pragma unroll
    for (int jj = 0; jj < 4; jj++) pv[jj] = f2bf(xs[j + jj]);
    *(u16x4*)&Pb[row * VST + sub * SL + j] = pv;
  }
  __syncthreads();

  // --- phase 3: out = (P . Vt^T) * Rps[row] ---
  constexpr int TT2 = (L / 16) * 4;
  for (int tt = w; tt < TT2; tt += 4) {
    int m = tt >> 2, n = tt & 3;
    f32x4 a = {0.f, 0.f, 0.f, 0.f};
#pragma unroll
    for (int ks = 0; ks < SP / 32; ks++) {
      bf16x8 af = *(const bf16x8*)&Pb[(m * 16 + ra) * VST + ks * 32 + ka];
      bf16x8 bf = *(const bf16x8*)&Vt[(n * 16 + ra) * VST + ks * 32 + ka];
      a = __builtin_amdgcn_mfma_f32_16x16x32_bf16(af, bf, a, 0, 0, 0);
    }
#pragma unroll
    for (int i = 0; i < 4; i++) {
      int l = m * 16 + cr + i, e = n * 16 + cc;
      float val = a[i] * Rps[l];
      int l_new = h * (L / 16) + (l >> 4);
      int cg = (l & 15) * 64 + e;
      Out[((size_t)(batch * L + l_new)) * 1024 + cg] = f2bf(val);
    }
  }
}

// ---------------- LayerNorm(a+b) * g + be, optional row permutation / f32 out ----------------
// MODE 0: orow=r. MODE 1: r=(b,t,s) dims(32,64) -> orow=(b,s,t). MODE 2: r=(b,s,t) dims(64,32) -> orow=(b,t,s).
template <int MODE, bool F32OUT>
__global__ __launch_bounds__(256) void k_ln(const unsigned short* __restrict__ a,
                                            const unsigned short* __restrict__ b,
                                            const float* __restrict__ g,
                                            const float* __restrict__ be,
                                            void* __restrict__ outp) {
  __shared__ float red[8];
  int r = blockIdx.x, t = threadIdx.x;
  size_t base = (size_t)r * 1024 + t * 4;
  u16x4 av = *(const u16x4*)(a + base);
  u16x4 bv = *(const u16x4*)(b + base);
  float x[4];
  float s = 0.f, ss = 0.f;
#pragma unroll
  for (int i = 0; i < 4; i++) {
    x[i] = bf2f(av[i]) + bf2f(bv[i]);
    s += x[i]; ss += x[i] * x[i];
  }
#pragma unroll
  for (int o = 32; o; o >>= 1) { s += __shfl_xor(s, o); ss += __shfl_xor(ss, o); }
  int w = t >> 6;
  if ((t & 63) == 0) { red[w] = s; red[4 + w] = ss; }
  __syncthreads();
  s = red[0] + red[1] + red[2] + red[3];
  ss = red[4] + red[5] + red[6] + red[7];
  float mean = s * (1.f / 1024.f);
  float var = ss * (1.f / 1024.f) - mean * mean;
  float rstd = rsqrtf(var + 1e-5f);
  int orow;
  if (MODE == 0) orow = r;
  else if (MODE == 1) { int bi = r >> 11, rem = r & 2047; int tt = rem >> 6, sd = rem & 63; orow = (bi << 11) + sd * 32 + tt; }
  else { int bi = r >> 11, rem = r & 2047; int sd = rem >> 5, tt = rem & 31; orow = (bi << 11) + tt * 64 + sd; }
  size_t ob = (size_t)orow * 1024 + t * 4;
  if (F32OUT) {
    f32x4 y;
#pragma unroll
    for (int i = 0; i < 4; i++) y[i] = (x[i] - mean) * rstd * g[t * 4 + i] + be[t * 4 + i];
    *(f32x4*)((float*)outp + ob) = y;
  } else {
    u16x4 y;
#pragma unroll
    for (int i = 0; i < 4; i++) y[i] = f2bf((x[i] - mean) * rstd * g[t * 4 + i] + be[t * 4 + i]);
    *(u16x4*)((unsigned short*)outp + ob) = y;
  }
}

// =======================================================================================

extern "C" void kernel_launch(void* const* d_in, const int* in_sizes, int n_in,
                              void* d_out, int out_size, void* d_ws, size_t ws_size,
                              hipStream_t stream) {
  // dims: b=8, ts_d=32, seg=64, d=1024, h=16, dff=4096, factor=10
  const int M = 16384;
  if (n_in < 43 || in_sizes[0] != 16777216 || in_sizes[25] != 10240 || in_sizes[34] != 4194304) {
    fprintf(stderr, "kernel_launch: unexpected input layout (n_in=%d)\n", n_in);
    return;
  }
  const float* x = (const float*)d_in[0];
  const float* w[3][4]; const float* bia[3][4];
  for (int p = 0; p < 3; p++) {
    w[p][0] = (const float*)d_in[1 + 8 * p + 0]; bia[p][0] = (const float*)d_in[1 + 8 * p + 1];
    w[p][1] = (const float*)d_in[1 + 8 * p + 2]; bia[p][1] = (const float*)d_in[1 + 8 * p + 3];
    w[p][2] = (const float*)d_in[1 + 8 * p + 4]; bia[p][2] = (const float*)d_in[1 + 8 * p + 5];
    w[p][3] = (const float*)d_in[1 + 8 * p + 6]; bia[p][3] = (const float*)d_in[1 + 8 * p + 7];
  }
  const float* cs_key = (const float*)d_in[25];
  const float* ng[4]; const float* nb[4];
  for (int i = 0; i < 4; i++) { ng[i] = (const float*)d_in[26 + 2 * i]; nb[i] = (const float*)d_in[27 + 2 * i]; }
  const float* m_w1[2]; const float* m_b1[2]; const float* m_w2[2]; const float* m_b2[2];
  for (int i = 0; i < 2; i++) {
    m_w1[i] = (const float*)d_in[34 + 4 * i]; m_b1[i] = (const float*)d_in[35 + 4 * i];
    m_w2[i] = (const float*)d_in[36 + 4 * i]; m_b2[i] = (const float*)d_in[37 + 4 * i];
  }

  // ---- workspace bump allocator (~224 MiB of 256) ----
  char* base = (char*)d_ws; size_t off = 0;
  auto alloc = [&](size_t bytes) -> void* {
    off = (off + 255) & ~(size_t)255;
    void* p = base + off; off += bytes; return p;
  };
  const size_t W1M = (size_t)1024 * 1024;  // elements in a 1024x1024 bf16 block
  unsigned short* W3ct = (unsigned short*)alloc(3 * W1M * 2);  // [wqT; wkT; wkvT]
  unsigned short* W3hp = (unsigned short*)alloc(3 * W1M * 2);
  unsigned short* Woct = (unsigned short*)alloc(W1M * 2);
  unsigned short* Wohp = (unsigned short*)alloc(W1M * 2);
  unsigned short* Wocs = (unsigned short*)alloc(W1M * 2);
  unsigned short* Wqcs = (unsigned short*)alloc(W1M * 2);
  unsigned short* Wkcs = (unsigned short*)alloc(W1M * 2);
  unsigned short* Wvcs = (unsigned short*)alloc(W1M * 2);
  unsigned short* Wm1u = (unsigned short*)alloc((size_t)4096 * 1024 * 2);
  unsigned short* Wm1d = (unsigned short*)alloc((size_t)1024 * 4096 * 2);
  unsigned short* Wm2u = (unsigned short*)alloc((size_t)4096 * 1024 * 2);
  unsigned short* Wm2d = (unsigned short*)alloc((size_t)1024 * 4096 * 2);
  unsigned short* Wvt_ct = (unsigned short*)alloc(W1M * 2);  // wv^T (fold A operand)
  unsigned short* Wraw_ct = (unsigned short*)alloc(W1M * 2); // wk cast (fold Bt operand)
  unsigned short* Wvt_hp = (unsigned short*)alloc(W1M * 2);
  unsigned short* Wraw_hp = (unsigned short*)alloc(W1M * 2);
  float* b3ct = (float*)alloc(3072 * 4);
  float* b3hp = (float*)alloc(3072 * 4);
  unsigned short* P[5];
  for (int i = 0; i < 5; i++) P[i] = (unsigned short*)alloc((size_t)M * 1024 * 2);  // contiguous pool
  unsigned short* KeyB = (unsigned short*)alloc((size_t)10 * 1024 * 2);
  unsigned short* Kcs = (unsigned short*)alloc((size_t)10 * 1024 * 2);
  unsigned short* Vcs = (unsigned short*)alloc((size_t)10 * 1024 * 2);
  if (off > ws_size) {
    fprintf(stderr, "kernel_launch: ws too small: need %zu have %zu\n", off, ws_size);
    return;
  }
  const int MC = 8192;  // MLP chunk rows; hidden (64 MiB) aliased over two dead pool slots

  auto gemm = [&](const unsigned short* Ap, const unsigned short* Bt, const float* bi,
                  unsigned short* Cp, int Mm, int Nn, int Kk, bool gelu) {
    dim3 gg(Nn / 128, Mm / 128);
    if (gelu) k_gemm<true><<<gg, 256, 0, stream>>>(Ap, Bt, bi, Cp, Mm, Nn, Kk);
    else      k_gemm<false><<<gg, 256, 0, stream>>>(Ap, Bt, bi, Cp, Mm, Nn, Kk);
  };
  auto tc = [&](const float* src, unsigned short* dst) {  // 1024x1024 transpose-cast
    k_tcast<<<dim3(32, 32), 256, 0, stream>>>(src, dst, 1024, 1024);
  };

  // ---- weight prep ----
  tc(w[0][0], W3ct); tc(w[0][1], W3ct + W1M);          // ct wq^T, wk^T
  tc(w[2][0], W3hp); tc(w[2][1], W3hp + W1M);          // hp wq^T, wk^T
  tc(w[0][3], Woct); tc(w[2][3], Wohp); tc(w[1][3], Wocs);
  tc(w[1][0], Wqcs); tc(w[1][1], Wkcs); tc(w[1][2], Wvcs);
  k_tcast<<<dim3(128, 32), 256, 0, stream>>>(m_w1[0], Wm1u, 1024, 4096);
  k_tcast<<<dim3(32, 128), 256, 0, stream>>>(m_w2[0], Wm1d, 4096, 1024);
  k_tcast<<<dim3(128, 32), 256, 0, stream>>>(m_w1[1], Wm2u, 1024, 4096);
  k_tcast<<<dim3(32, 128), 256, 0, stream>>>(m_w2[1], Wm2d, 4096, 1024);
  tc(w[0][2], Wvt_ct); k_cast<<<1024, 256, 0, stream>>>(w[0][1], Wraw_ct, 262144);
  tc(w[2][2], Wvt_hp); k_cast<<<1024, 256, 0, stream>>>(w[2][1], Wraw_hp, 262144);
  k_cast<<<16384, 256, 0, stream>>>(x, P[0], 16777216 / 4);
  k_cast<<<10, 256, 0, stream>>>(cs_key, KeyB, 10240 / 4);
  // folded V weights: Wkv^T[n][i] = sum_j wv^T[n][j] * wk[i][j]  -> rows 2048.. of W3
  gemm(Wvt_ct, Wraw_ct, nullptr, W3ct + 2 * W1M, 1024, 1024, 1024, false);
  gemm(Wvt_hp, Wraw_hp, nullptr, W3hp + 2 * W1M, 1024, 1024, 1024, false);
  // folded biases: b3 = [bq; bk; bk@wv + bv]
  k_cpb<<<4, 256, 0, stream>>>(bia[0][0], bia[0][1], b3ct);
  k_bfold<<<4, 256, 0, stream>>>(bia[0][1], w[0][2], bia[0][2], b3ct + 2048);
  k_cpb<<<4, 256, 0, stream>>>(bia[2][0], bia[2][1], b3hp);
  k_bfold<<<4, 256, 0, stream>>>(bia[2][1], w[2][2], bia[2][2], b3hp + 2048);
  k_gemm10<<<dim3(10, 16), 256, 0, stream>>>(KeyB, Wkcs, bia[1][1], Kcs);   // Kcs
  k_gemm10<<<dim3(10, 16), 256, 0, stream>>>(Kcs, Wvcs, bia[1][2], Vcs);    // Vcs

  // ---- stage T (L=S=64 attention over seg) ----
  gemm(P[0], W3ct, b3ct, P[1], M, 3072, 1024, false);                       // QKV (P1..P3)
  k_attn<64, 64, false><<<256 * 16, 256, 0, stream>>>(P[1], P[1] + 1024, P[1] + 2048, P[4], 3072);
  gemm(P[4], Woct, bia[0][3], P[1], M, 1024, 1024, false);                  // time_enc -> P1
  k_ln<0, false><<<M, 256, 0, stream>>>(P[0], P[1], ng[0], nb[0], P[2]);    // D = LN(x+enc) -> P2
  for (int c = 0; c < M; c += MC) {                                         // R = mlp(D) -> P1
    gemm(P[2] + (size_t)c * 1024, Wm1u, m_b1[0], P[3], MC, 4096, 1024, true);   // H at P3..P4
    gemm(P[3], Wm1d, m_b2[0], P[1] + (size_t)c * 1024, MC, 1024, 4096, false);
  }
  k_ln<1, false><<<M, 256, 0, stream>>>(P[2], P[1], ng[1], nb[1], P[3]);    // S_in -> P3 (permuted)

  // ---- stage S (L=32) ----
  gemm(P[3], W3hp, b3hp, P[0], M, 3072, 1024, false);                       // QKVhp (P0..P2)
  k_attn<32, 32, false><<<512 * 16, 256, 0, stream>>>(P[0], P[0] + 1024, P[0] + 2048, P[4], 3072);
  gemm(P[4], Wohp, bia[2][3], P[1], M, 1024, 1024, false);                  // PH -> P1
  gemm(P[3], Wqcs, bia[1][0], P[2], M, 1024, 1024, false);                  // Qcs -> P2
  k_attn<32, 10, true><<<512 * 16, 256, 0, stream>>>(P[2], Kcs, Vcs, P[0], 1024);
  gemm(P[0], Wocs, bia[1][3], P[2], M, 1024, 1024, false);                  // SH -> P2
  k_ln<0, false><<<M, 256, 0, stream>>>(P[2], P[1], ng[2], nb[2], P[0]);    // DE -> P0
  for (int c = 0; c < M; c += MC) {                                         // R2 = mlp(DE) -> P1
    gemm(P[0] + (size_t)c * 1024, Wm2u, m_b1[1], P[2], MC, 4096, 1024, true);   // H at P2..P3
    gemm(P[2], Wm2d, m_b2[1], P[1] + (size_t)c * 1024, MC, 1024, 4096, false);
  }
  k_ln<2, true><<<M, 256, 0, stream>>>(P[0], P[1], ng[3], nb[3], d_out);    // final LN+permute f32
}

// Round 9
// 1824.664 us; speedup vs baseline: 1.0077x; 1.0077x over previous
//
#include <hip/hip_runtime.h>
#include <cstdio>

typedef __bf16 bf16x8 __attribute__((ext_vector_type(8)));
typedef float f32x4 __attribute__((ext_vector_type(4)));
typedef int i32x4 __attribute__((ext_vector_type(4)));
typedef unsigned short u16x4 __attribute__((ext_vector_type(4)));

__device__ __forceinline__ float bf2f(unsigned short u) {
  union { unsigned int i; float f; } x; x.i = ((unsigned int)u) << 16; return x.f;
}
__device__ __forceinline__ unsigned short f2bf(float f) {
  union { float f; unsigned int i; } x; x.f = f;
  unsigned int r = x.i + 0x7fffu + ((x.i >> 16) & 1u);
  return (unsigned short)(r >> 16);
}

// async global->LDS, 16B per lane; LDS dest is wave-uniform base + lane*16
__device__ __forceinline__ void gl2lds16(const unsigned short* g, unsigned short* l) {
  __builtin_amdgcn_global_load_lds((const __attribute__((address_space(1))) unsigned int*)g,
                                   (__attribute__((address_space(3))) unsigned int*)l, 16, 0, 0);
}

// ---------------- elementwise f32 -> bf16 cast (vec4) ----------------
__global__ __launch_bounds__(256) void k_cast(const float* __restrict__ in,
                                              unsigned short* __restrict__ out, int n4) {
  int i = blockIdx.x * 256 + threadIdx.x;
  if (i >= n4) return;
  f32x4 v = ((const f32x4*)in)[i];
  u16x4 o;
  o[0] = f2bf(v[0]); o[1] = f2bf(v[1]); o[2] = f2bf(v[2]); o[3] = f2bf(v[3]);
  ((u16x4*)out)[i] = o;
}

// -------- transpose-cast: src f32 [K][N] -> dst bf16 [N][K] --------
__global__ __launch_bounds__(256) void k_tcast(const float* __restrict__ src,
                                               unsigned short* __restrict__ dst,
                                               int K, int N) {
  __shared__ float tile[32][33];
  int gx = blockIdx.x * 32;  // N dim
  int gy = blockIdx.y * 32;  // K dim
  int t = threadIdx.x;
  int c = t & 31, r0 = t >> 5;
#pragma unroll
  for (int i = 0; i < 4; i++) {
    int r = r0 + i * 8;
    tile[r][c] = src[(size_t)(gy + r) * N + gx + c];
  }
  __syncthreads();
#pragma unroll
  for (int i = 0; i < 4; i++) {
    int r = r0 + i * 8;
    dst[(size_t)(gx + r) * K + gy + c] = f2bf(tile[c][r]);
  }
}

// ---- folded bias: out[n] = bv[n] + sum_j bk[j]*wv[j][n]  (f32, 1024 wide) ----
__global__ __launch_bounds__(256) void k_bfold(const float* __restrict__ bk,
                                               const float* __restrict__ wv,
                                               const float* __restrict__ bv,
                                               float* __restrict__ out) {
  int n = blockIdx.x * 256 + threadIdx.x;
  float acc = bv[n];
#pragma unroll 8
  for (int j = 0; j < 1024; j++) acc += bk[j] * wv[(size_t)j * 1024 + n];
  out[n] = acc;
}

// ---- concat two 1024-f32 vectors into out[0..2047] ----
__global__ __launch_bounds__(256) void k_cpb(const float* __restrict__ a,
                                             const float* __restrict__ b,
                                             float* __restrict__ out) {
  int t = blockIdx.x * 256 + threadIdx.x;
  out[t] = a[t];
  out[1024 + t] = b[t];
}

// ======== MFMA GEMM: 128x128 tile, BK=32, ring-3 LDS, TRUE counted vmcnt ========
// C[M][N] = A[M][K](bf16 rm) * Bt[N][K]^T + bias (opt exact GELU); bias may be null (=0).
// 256 threads = 4 waves (2x2), wave tile 64x64 via 4x4 mfma 16x16x32.
// KEY (r9): raw s_barrier (no implicit vmcnt(0) drain that __syncthreads emits) +
// per-wave counted vmcnt(4). Each wave verifies ITS OWN tile-j loads complete before the
// barrier => after barrier all waves' tile-j loads are resident. Stage j+2 (into buf
// (j-1)%3) after the barrier is race-free: that buffer's ds_reads were consumed by
// iter j-1 MFMAs (compiler lgkm waits) before any wave reached barrier j.
template <bool GELU>
__global__ __launch_bounds__(256) void k_gemm(const unsigned short* __restrict__ A,
                                              const unsigned short* __restrict__ Bt,
                                              const float* __restrict__ bias,
                                              unsigned short* __restrict__ C,
                                              int M, int N, int K) {
  __shared__ unsigned short As[3][128 * 32];
  __shared__ unsigned short Bs[3][128 * 32];
  const int rowA0 = blockIdx.y * 128, colB0 = blockIdx.x * 128;
  const int t = threadIdx.x, w = t >> 6, lane = t & 63;
  const int wr = w >> 1, wc = w & 1;
  const int srow = w * 16 + (lane >> 2);
  const int schunk = (lane & 3) ^ ((lane >> 3) & 3);  // granule ^ ((row>>1)&3)
  const unsigned short* pa = A + (size_t)(rowA0 + srow) * K + schunk * 8;
  const unsigned short* pb = Bt + (size_t)(colB0 + srow) * K + schunk * 8;
  const size_t row64 = (size_t)64 * K;

  f32x4 acc[4][4] = {};
  const int g = lane >> 4, ra = lane & 15;
  const int gp8 = (g ^ ((ra >> 1) & 3)) * 8;  // read-side inverse swizzle

  auto stage = [&](int buf, int kk) {
    gl2lds16(pa + kk,         &As[buf][w * 512]);
    gl2lds16(pa + row64 + kk, &As[buf][2048 + w * 512]);
    gl2lds16(pb + kk,         &Bs[buf][w * 512]);
    gl2lds16(pb + row64 + kk, &Bs[buf][2048 + w * 512]);
  };

  const int NT = K >> 5;
  stage(0, 0);
  if (NT > 1) stage(1, 32);
  int cur = 0;
  for (int j = 0; j < NT; ++j) {
    // own tile-j loads (4 instrs) complete; tile j+1's 4 may remain in flight
    if (j + 1 < NT) asm volatile("s_waitcnt vmcnt(4)" ::: "memory");
    else            asm volatile("s_waitcnt vmcnt(0)" ::: "memory");
    __builtin_amdgcn_sched_barrier(0);
    __builtin_amdgcn_s_barrier();          // raw: no compiler-inserted drain
    __builtin_amdgcn_sched_barrier(0);
    if (j + 2 < NT) {
      int nb = cur + 2; if (nb >= 3) nb -= 3;
      stage(nb, (j + 2) * 32);             // overwrites buf (j-1)%3: reads done pre-barrier
    }
    bf16x8 af[4], bfr[4];
#pragma unroll
    for (int m = 0; m < 4; m++)
      af[m] = *(const bf16x8*)&As[cur][(wr * 64 + m * 16 + ra) * 32 + gp8];
#pragma unroll
    for (int n = 0; n < 4; n++)
      bfr[n] = *(const bf16x8*)&Bs[cur][(wc * 64 + n * 16 + ra) * 32 + gp8];
#pragma unroll
    for (int m = 0; m < 4; m++)
#pragma unroll
      for (int n = 0; n < 4; n++)
        acc[m][n] = __builtin_amdgcn_mfma_f32_16x16x32_bf16(af[m], bfr[n], acc[m][n], 0, 0, 0);
    cur += 1; if (cur >= 3) cur -= 3;
  }
  asm volatile("s_waitcnt vmcnt(0) lgkmcnt(0)" ::: "memory");
  __builtin_amdgcn_s_barrier();            // before epilogue scratch reuse

  // ---- epilogue: per-wave LDS transpose (XOR-swizzled), 16B coalesced stores ----
  unsigned short* Ep = &As[0][0] + w * 1024;  // 16x64 u16 region per wave
  const int grow0 = rowA0 + wr * 64;
  const int gcol0 = colB0 + wc * 64;
  float bv[4];
#pragma unroll
  for (int n = 0; n < 4; n++) bv[n] = bias ? bias[gcol0 + n * 16 + ra] : 0.f;
  const int rdrow = lane >> 3, rg = lane & 7;
#pragma unroll
  for (int m = 0; m < 4; m++) {
#pragma unroll
    for (int n = 0; n < 4; n++)
#pragma unroll
      for (int i = 0; i < 4; i++) {
        int r = g * 4 + i;
        float v = acc[m][n][i] + bv[n];
        if (GELU) v = 0.5f * v * (1.f + erff(v * 0.70710678118654752f));
        Ep[r * 64 + ((ra + n * 16) ^ ((r & 7) << 3))] = f2bf(v);
      }
    asm volatile("s_waitcnt lgkmcnt(0)" ::: "memory");  // wave-local: writes visible to all lanes
    __builtin_amdgcn_sched_barrier(0);
#pragma unroll
    for (int p = 0; p < 2; p++) {
      int rr = p * 8 + rdrow;
      bf16x8 val = *(const bf16x8*)&Ep[rr * 64 + ((rg ^ (rr & 7)) << 3)];
      *(bf16x8*)&C[(size_t)(grow0 + m * 16 + rr) * N + gcol0 + rg * 8] = val;
    }
    asm volatile("s_waitcnt lgkmcnt(0)" ::: "memory");  // reads done before next slice overwrites
  }
}

// ---------------- small GEMM (M<=10): C[Mr][1024] = A[Mr][1024] * Wt^T + bias ----------------
__global__ __launch_bounds__(256) void k_gemm10(const unsigned short* __restrict__ A,
                                                const unsigned short* __restrict__ Bt,
                                                const float* __restrict__ bias,
                                                unsigned short* __restrict__ C) {
  __shared__ float af[1024];
  int m = blockIdx.x, nb = blockIdx.y;
  int t = threadIdx.x;
#pragma unroll
  for (int i = 0; i < 4; i++) af[t * 4 + i] = bf2f(A[(size_t)m * 1024 + t * 4 + i]);
  __syncthreads();
  int w = t >> 6, lane = t & 63;
  for (int n = nb * 64 + w; n < nb * 64 + 64; n += 4) {
    const unsigned short* brow = Bt + (size_t)n * 1024 + lane * 16;
    float acc = 0.f;
#pragma unroll
    for (int j = 0; j < 16; j++) acc += af[lane * 16 + j] * bf2f(brow[j]);
#pragma unroll
    for (int o = 32; o; o >>= 1) acc += __shfl_xor(acc, o);
    if (lane == 0) C[(size_t)m * 1024 + n] = f2bf(acc + bias[n]);
  }
}

// ---------------- entmax-1.5 attention, MFMA version (RS = input row stride) ----------------
// Output in torch Hopfield "mix" layout: out[batch][h*(L/16)+l/16][(l%16)*64+e], stride 1024.
template <int L, int S, bool SHARED>
__global__ __launch_bounds__(256) void k_attn(const unsigned short* __restrict__ Q,
                                              const unsigned short* __restrict__ Kb,
                                              const unsigned short* __restrict__ Vb,
                                              unsigned short* __restrict__ Out, int RS) {
  constexpr int SP = (S <= 32) ? 32 : 64;  // S padded to MFMA K-multiple
  constexpr int QST = 72;                  // Q/K row stride (bf16), pad for bank spread
  constexpr int VST = SP + 8;              // Vt/P row stride
  constexpr int CST = SP + 4;              // scores row stride (f32)
  __shared__ unsigned short Qs[L * QST];   // reused as P (stride VST) in phase 3
  __shared__ unsigned short Ks[SP * QST];
  __shared__ unsigned short Vt[64 * VST];  // Vt[e][s] = V[s][e]
  __shared__ float Sc[L * CST];
  __shared__ float Rps[L];
  const int blk = blockIdx.x, batch = blk >> 4, h = blk & 15;
  const int t = threadIdx.x, w = t >> 6, lane = t & 63;

  // --- stage Q (16B chunks) ---
  for (int c = t; c < L * 8; c += 256) {
    int r = c >> 3, ch = (c & 7) * 8;
    *(i32x4*)&Qs[r * QST + ch] =
        *(const i32x4*)&Q[((size_t)(batch * L + r)) * RS + h * 64 + ch];
  }
  // --- stage K rows (zero rows >= S) ---
  for (int c = t; c < SP * 8; c += 256) {
    int r = c >> 3, ch = (c & 7) * 8;
    i32x4 v = {0, 0, 0, 0};
    if (r < S) {
      size_t rb = SHARED ? (size_t)r : (size_t)(batch * S + r);
      v = *(const i32x4*)&Kb[rb * RS + h * 64 + ch];
    }
    *(i32x4*)&Ks[r * QST + ch] = v;
  }
  // --- stage V transposed (zero cols >= S) ---
  for (int c = t; c < SP * 64; c += 256) {
    int s = c >> 6, e = c & 63;
    unsigned short v = 0;
    if (s < S) {
      size_t rb = SHARED ? (size_t)s : (size_t)(batch * S + s);
      v = Vb[rb * RS + h * 64 + e];
    }
    Vt[e * VST + s] = v;
  }
  __syncthreads();

  const int ka = (lane >> 4) * 8, ra = lane & 15;
  const int cr = (lane >> 4) * 4, cc = lane & 15;
  // --- phase 1: scores = (Q K^T) * 0.5/sqrt(64) ---
  constexpr int NT = SP / 16, TT = (L / 16) * NT;
  for (int tt = w; tt < TT; tt += 4) {
    int m = tt / NT, n = tt % NT;
    f32x4 a = {0.f, 0.f, 0.f, 0.f};
#pragma unroll
    for (int ks = 0; ks < 2; ks++) {  // E=64 -> 2 K-steps
      bf16x8 af = *(const bf16x8*)&Qs[(m * 16 + ra) * QST + ks * 32 + ka];
      bf16x8 bf = *(const bf16x8*)&Ks[(n * 16 + ra) * QST + ks * 32 + ka];
      a = __builtin_amdgcn_mfma_f32_16x16x32_bf16(af, bf, a, 0, 0, 0);
    }
#pragma unroll
    for (int i = 0; i < 4; i++)
      Sc[(m * 16 + cr + i) * CST + n * 16 + cc] = a[i] * 0.0625f;
  }
  __syncthreads();

  // --- phase 2: bisection, G lanes per row, scores in registers ---
  constexpr int G = 256 / L, RW = 64 / G, SL = SP / G;
  const int row = w * RW + lane / G, sub = lane % G;
  float xs[SL];
#pragma unroll
  for (int j = 0; j < SL; j++) {
    int s = sub * SL + j;
    float v = Sc[row * CST + s];
    if (S < SP && s >= S) v = -1e30f;
    xs[j] = v;
  }
  float mx = xs[0];
#pragma unroll
  for (int j = 1; j < SL; j++) mx = fmaxf(mx, xs[j]);
#pragma unroll
  for (int o = G / 2; o; o >>= 1) mx = fmaxf(mx, __shfl_xor(mx, o));
  const float hoff = (S == 64) ? 0.125f : (S == 32) ? 0.17677669529663687f : 0.31622776601683794f;
  float lo = mx - 1.f, hi = mx - hoff;
#pragma unroll 1
  for (int it = 0; it < 26; it++) {
    float mid = 0.5f * (lo + hi);
    float f = 0.f;
#pragma unroll
    for (int j = 0; j < SL; j++) { float dd = fmaxf(xs[j] - mid, 0.f); f += dd * dd; }
#pragma unroll
    for (int o = G / 2; o; o >>= 1) f += __shfl_xor(f, o);
    bool gt = f > 1.f;
    lo = gt ? mid : lo;
    hi = gt ? hi : mid;
  }
  float tau = 0.5f * (lo + hi);
  float ps = 0.f;
#pragma unroll
  for (int j = 0; j < SL; j++) { float dd = fmaxf(xs[j] - tau, 0.f); xs[j] = dd * dd; ps += xs[j]; }
#pragma unroll
  for (int o = G / 2; o; o >>= 1) ps += __shfl_xor(ps, o);
  if (sub == 0) Rps[row] = 1.f / ps;
  unsigned short* Pb = Qs;  // reuse Qs as P (unnormalized, bf16, stride VST)
#pragma unroll
  for (int j = 0; j < SL; j += 4) {
    u16x4 pv;
#pragma unroll
    for (int jj = 0; jj < 4; jj++) pv[jj] = f2bf(xs[j + jj]);
    *(u16x4*)&Pb[row * VST + sub * SL + j] = pv;
  }
  __syncthreads();

  // --- phase 3: out = (P . Vt^T) * Rps[row] ---
  constexpr int TT2 = (L / 16) * 4;
  for (int tt = w; tt < TT2; tt += 4) {
    int m = tt >> 2, n = tt & 3;
    f32x4 a = {0.f, 0.f, 0.f, 0.f};
#pragma unroll
    for (int ks = 0; ks < SP / 32; ks++) {
      bf16x8 af = *(const bf16x8*)&Pb[(m * 16 + ra) * VST + ks * 32 + ka];
      bf16x8 bf = *(const bf16x8*)&Vt[(n * 16 + ra) * VST + ks * 32 + ka];
      a = __builtin_amdgcn_mfma_f32_16x16x32_bf16(af, bf, a, 0, 0, 0);
    }
#pragma unroll
    for (int i = 0; i < 4; i++) {
      int l = m * 16 + cr + i, e = n * 16 + cc;
      float val = a[i] * Rps[l];
      int l_new = h * (L / 16) + (l >> 4);
      int cg = (l & 15) * 64 + e;
      Out[((size_t)(batch * L + l_new)) * 1024 + cg] = f2bf(val);
    }
  }
}

// ---------------- LayerNorm(a+b) * g + be, optional row permutation / f32 out ----------------
// MODE 0: orow=r. MODE 1: r=(b,t,s) dims(32,64) -> orow=(b,s,t). MODE 2: r=(b,s,t) dims(64,32) -> orow=(b,t,s).
template <int MODE, bool F32OUT>
__global__ __launch_bounds__(256) void k_ln(const unsigned short* __restrict__ a,
                                            const unsigned short* __restrict__ b,
                                            const float* __restrict__ g,
                                            const float* __restrict__ be,
                                            void* __restrict__ outp) {
  __shared__ float red[8];
  int r = blockIdx.x, t = threadIdx.x;
  size_t base = (size_t)r * 1024 + t * 4;
  u16x4 av = *(const u16x4*)(a + base);
  u16x4 bv = *(const u16x4*)(b + base);
  float x[4];
  float s = 0.f, ss = 0.f;
#pragma unroll
  for (int i = 0; i < 4; i++) {
    x[i] = bf2f(av[i]) + bf2f(bv[i]);
    s += x[i]; ss += x[i] * x[i];
  }
#pragma unroll
  for (int o = 32; o; o >>= 1) { s += __shfl_xor(s, o); ss += __shfl_xor(ss, o); }
  int w = t >> 6;
  if ((t & 63) == 0) { red[w] = s; red[4 + w] = ss; }
  __syncthreads();
  s = red[0] + red[1] + red[2] + red[3];
  ss = red[4] + red[5] + red[6] + red[7];
  float mean = s * (1.f / 1024.f);
  float var = ss * (1.f / 1024.f) - mean * mean;
  float rstd = rsqrtf(var + 1e-5f);
  int orow;
  if (MODE == 0) orow = r;
  else if (MODE == 1) { int bi = r >> 11, rem = r & 2047; int tt = rem >> 6, sd = rem & 63; orow = (bi << 11) + sd * 32 + tt; }
  else { int bi = r >> 11, rem = r & 2047; int sd = rem >> 5, tt = rem & 31; orow = (bi << 11) + tt * 64 + sd; }
  size_t ob = (size_t)orow * 1024 + t * 4;
  if (F32OUT) {
    f32x4 y;
#pragma unroll
    for (int i = 0; i < 4; i++) y[i] = (x[i] - mean) * rstd * g[t * 4 + i] + be[t * 4 + i];
    *(f32x4*)((float*)outp + ob) = y;
  } else {
    u16x4 y;
#pragma unroll
    for (int i = 0; i < 4; i++) y[i] = f2bf((x[i] - mean) * rstd * g[t * 4 + i] + be[t * 4 + i]);
    *(u16x4*)((unsigned short*)outp + ob) = y;
  }
}

// =======================================================================================

extern "C" void kernel_launch(void* const* d_in, const int* in_sizes, int n_in,
                              void* d_out, int out_size, void* d_ws, size_t ws_size,
                              hipStream_t stream) {
  // dims: b=8, ts_d=32, seg=64, d=1024, h=16, dff=4096, factor=10
  const int M = 16384;
  if (n_in < 43 || in_sizes[0] != 16777216 || in_sizes[25] != 10240 || in_sizes[34] != 4194304) {
    fprintf(stderr, "kernel_launch: unexpected input layout (n_in=%d)\n", n_in);
    return;
  }
  const float* x = (const float*)d_in[0];
  const float* w[3][4]; const float* bia[3][4];
  for (int p = 0; p < 3; p++) {
    w[p][0] = (const float*)d_in[1 + 8 * p + 0]; bia[p][0] = (const float*)d_in[1 + 8 * p + 1];
    w[p][1] = (const float*)d_in[1 + 8 * p + 2]; bia[p][1] = (const float*)d_in[1 + 8 * p + 3];
    w[p][2] = (const float*)d_in[1 + 8 * p + 4]; bia[p][2] = (const float*)d_in[1 + 8 * p + 5];
    w[p][3] = (const float*)d_in[1 + 8 * p + 6]; bia[p][3] = (const float*)d_in[1 + 8 * p + 7];
  }
  const float* cs_key = (const float*)d_in[25];
  const float* ng[4]; const float* nb[4];
  for (int i = 0; i < 4; i++) { ng[i] = (const float*)d_in[26 + 2 * i]; nb[i] = (const float*)d_in[27 + 2 * i]; }
  const float* m_w1[2]; const float* m_b1[2]; const float* m_w2[2]; const float* m_b2[2];
  for (int i = 0; i < 2; i++) {
    m_w1[i] = (const float*)d_in[34 + 4 * i]; m_b1[i] = (const float*)d_in[35 + 4 * i];
    m_w2[i] = (const float*)d_in[36 + 4 * i]; m_b2[i] = (const float*)d_in[37 + 4 * i];
  }

  // ---- workspace bump allocator (~224 MiB of 256) ----
  char* base = (char*)d_ws; size_t off = 0;
  auto alloc = [&](size_t bytes) -> void* {
    off = (off + 255) & ~(size_t)255;
    void* p = base + off; off += bytes; return p;
  };
  const size_t W1M = (size_t)1024 * 1024;  // elements in a 1024x1024 bf16 block
  unsigned short* W3ct = (unsigned short*)alloc(3 * W1M * 2);  // [wqT; wkT; wkvT]
  unsigned short* W3hp = (unsigned short*)alloc(3 * W1M * 2);
  unsigned short* Woct = (unsigned short*)alloc(W1M * 2);
  unsigned short* Wohp = (unsigned short*)alloc(W1M * 2);
  unsigned short* Wocs = (unsigned short*)alloc(W1M * 2);
  unsigned short* Wqcs = (unsigned short*)alloc(W1M * 2);
  unsigned short* Wkcs = (unsigned short*)alloc(W1M * 2);
  unsigned short* Wvcs = (unsigned short*)alloc(W1M * 2);
  unsigned short* Wm1u = (unsigned short*)alloc((size_t)4096 * 1024 * 2);
  unsigned short* Wm1d = (unsigned short*)alloc((size_t)1024 * 4096 * 2);
  unsigned short* Wm2u = (unsigned short*)alloc((size_t)4096 * 1024 * 2);
  unsigned short* Wm2d = (unsigned short*)alloc((size_t)1024 * 4096 * 2);
  unsigned short* Wvt_ct = (unsigned short*)alloc(W1M * 2);  // wv^T (fold A operand)
  unsigned short* Wraw_ct = (unsigned short*)alloc(W1M * 2); // wk cast (fold Bt operand)
  unsigned short* Wvt_hp = (unsigned short*)alloc(W1M * 2);
  unsigned short* Wraw_hp = (unsigned short*)alloc(W1M * 2);
  float* b3ct = (float*)alloc(3072 * 4);
  float* b3hp = (float*)alloc(3072 * 4);
  unsigned short* P[5];
  for (int i = 0; i < 5; i++) P[i] = (unsigned short*)alloc((size_t)M * 1024 * 2);  // contiguous pool
  unsigned short* KeyB = (unsigned short*)alloc((size_t)10 * 1024 * 2);
  unsigned short* Kcs = (unsigned short*)alloc((size_t)10 * 1024 * 2);
  unsigned short* Vcs = (unsigned short*)alloc((size_t)10 * 1024 * 2);
  if (off > ws_size) {
    fprintf(stderr, "kernel_launch: ws too small: need %zu have %zu\n", off, ws_size);
    return;
  }
  const int MC = 8192;  // MLP chunk rows; hidden (64 MiB) aliased over two dead pool slots

  auto gemm = [&](const unsigned short* Ap, const unsigned short* Bt, const float* bi,
                  unsigned short* Cp, int Mm, int Nn, int Kk, bool gelu) {
    dim3 gg(Nn / 128, Mm / 128);
    if (gelu) k_gemm<true><<<gg, 256, 0, stream>>>(Ap, Bt, bi, Cp, Mm, Nn, Kk);
    else      k_gemm<false><<<gg, 256, 0, stream>>>(Ap, Bt, bi, Cp, Mm, Nn, Kk);
  };
  auto tc = [&](const float* src, unsigned short* dst) {  // 1024x1024 transpose-cast
    k_tcast<<<dim3(32, 32), 256, 0, stream>>>(src, dst, 1024, 1024);
  };

  // ---- weight prep ----
  tc(w[0][0], W3ct); tc(w[0][1], W3ct + W1M);          // ct wq^T, wk^T
  tc(w[2][0], W3hp); tc(w[2][1], W3hp + W1M);          // hp wq^T, wk^T
  tc(w[0][3], Woct); tc(w[2][3], Wohp); tc(w[1][3], Wocs);
  tc(w[1][0], Wqcs); tc(w[1][1], Wkcs); tc(w[1][2], Wvcs);
  k_tcast<<<dim3(128, 32), 256, 0, stream>>>(m_w1[0], Wm1u, 1024, 4096);
  k_tcast<<<dim3(32, 128), 256, 0, stream>>>(m_w2[0], Wm1d, 4096, 1024);
  k_tcast<<<dim3(128, 32), 256, 0, stream>>>(m_w1[1], Wm2u, 1024, 4096);
  k_tcast<<<dim3(32, 128), 256, 0, stream>>>(m_w2[1], Wm2d, 4096, 1024);
  tc(w[0][2], Wvt_ct); k_cast<<<1024, 256, 0, stream>>>(w[0][1], Wraw_ct, 262144);
  tc(w[2][2], Wvt_hp); k_cast<<<1024, 256, 0, stream>>>(w[2][1], Wraw_hp, 262144);
  k_cast<<<16384, 256, 0, stream>>>(x, P[0], 16777216 / 4);
  k_cast<<<10, 256, 0, stream>>>(cs_key, KeyB, 10240 / 4);
  // folded V weights: Wkv^T[n][i] = sum_j wv^T[n][j] * wk[i][j]  -> rows 2048.. of W3
  gemm(Wvt_ct, Wraw_ct, nullptr, W3ct + 2 * W1M, 1024, 1024, 1024, false);
  gemm(Wvt_hp, Wraw_hp, nullptr, W3hp + 2 * W1M, 1024, 1024, 1024, false);
  // folded biases: b3 = [bq; bk; bk@wv + bv]
  k_cpb<<<4, 256, 0, stream>>>(bia[0][0], bia[0][1], b3ct);
  k_bfold<<<4, 256, 0, stream>>>(bia[0][1], w[0][2], bia[0][2], b3ct + 2048);
  k_cpb<<<4, 256, 0, stream>>>(bia[2][0], bia[2][1], b3hp);
  k_bfold<<<4, 256, 0, stream>>>(bia[2][1], w[2][2], bia[2][2], b3hp + 2048);
  k_gemm10<<<dim3(10, 16), 256, 0, stream>>>(KeyB, Wkcs, bia[1][1], Kcs);   // Kcs
  k_gemm10<<<dim3(10, 16), 256, 0, stream>>>(Kcs, Wvcs, bia[1][2], Vcs);    // Vcs

  // ---- stage T (L=S=64 attention over seg) ----
  gemm(P[0], W3ct, b3ct, P[1], M, 3072, 1024, false);                       // QKV (P1..P3)
  k_attn<64, 64, false><<<256 * 16, 256, 0, stream>>>(P[1], P[1] + 1024, P[1] + 2048, P[4], 3072);
  gemm(P[4], Woct, bia[0][3], P[1], M, 1024, 1024, false);                  // time_enc -> P1
  k_ln<0, false><<<M, 256, 0, stream>>>(P[0], P[1], ng[0], nb[0], P[2]);    // D = LN(x+enc) -> P2
  for (int c = 0; c < M; c += MC) {                                         // R = mlp(D) -> P1
    gemm(P[2] + (size_t)c * 1024, Wm1u, m_b1[0], P[3], MC, 4096, 1024, true);   // H at P3..P4
    gemm(P[3], Wm1d, m_b2[0], P[1] + (size_t)c * 1024, MC, 1024, 4096, false);
  }
  k_ln<1, false><<<M, 256, 0, stream>>>(P[2], P[1], ng[1], nb[1], P[3]);    // S_in -> P3 (permuted)

  // ---- stage S (L=32) ----
  gemm(P[3], W3hp, b3hp, P[0], M, 3072, 1024, false);                       // QKVhp (P0..P2)
  k_attn<32, 32, false><<<512 * 16, 256, 0, stream>>>(P[0], P[0] + 1024, P[0] + 2048, P[4], 3072);
  gemm(P[4], Wohp, bia[2][3], P[1], M, 1024, 1024, false);                  // PH -> P1
  gemm(P[3], Wqcs, bia[1][0], P[2], M, 1024, 1024, false);                  // Qcs -> P2
  k_attn<32, 10, true><<<512 * 16, 256, 0, stream>>>(P[2], Kcs, Vcs, P[0], 1024);
  gemm(P[0], Wocs, bia[1][3], P[2], M, 1024, 1024, false);                  // SH -> P2
  k_ln<0, false><<<M, 256, 0, stream>>>(P[2], P[1], ng[2], nb[2], P[0]);    // DE -> P0
  for (int c = 0; c < M; c += MC) {                                         // R2 = mlp(DE) -> P1
    gemm(P[0] + (size_t)c * 1024, Wm2u, m_b1[1], P[2], MC, 4096, 1024, true);   // H at P2..P3
    gemm(P[2], Wm2d, m_b2[1], P[1] + (size_t)c * 1024, MC, 1024, 4096, false);
  }
  k_ln<2, true><<<M, 256, 0, stream>>>(P[0], P[1], ng[3], nb[3], d_out);    // final LN+permute f32
}

// Round 10
// 1670.768 us; speedup vs baseline: 1.1006x; 1.0921x over previous
//
#include <hip/hip_runtime.h>
#include <cstdio>

typedef __bf16 bf16x8 __attribute__((ext_vector_type(8)));
typedef float f32x4 __attribute__((ext_vector_type(4)));
typedef int i32x4 __attribute__((ext_vector_type(4)));
typedef unsigned short u16x4 __attribute__((ext_vector_type(4)));

__device__ __forceinline__ float bf2f(unsigned short u) {
  union { unsigned int i; float f; } x; x.i = ((unsigned int)u) << 16; return x.f;
}
__device__ __forceinline__ unsigned short f2bf(float f) {
  union { float f; unsigned int i; } x; x.f = f;
  unsigned int r = x.i + 0x7fffu + ((x.i >> 16) & 1u);
  return (unsigned short)(r >> 16);
}

// async global->LDS, 16B per lane; LDS dest is wave-uniform base + lane*16
__device__ __forceinline__ void gl2lds16(const unsigned short* g, unsigned short* l) {
  __builtin_amdgcn_global_load_lds((const __attribute__((address_space(1))) unsigned int*)g,
                                   (__attribute__((address_space(3))) unsigned int*)l, 16, 0, 0);
}

// ---------------- elementwise f32 -> bf16 cast (vec4) ----------------
__global__ __launch_bounds__(256) void k_cast(const float* __restrict__ in,
                                              unsigned short* __restrict__ out, int n4) {
  int i = blockIdx.x * 256 + threadIdx.x;
  if (i >= n4) return;
  f32x4 v = ((const f32x4*)in)[i];
  u16x4 o;
  o[0] = f2bf(v[0]); o[1] = f2bf(v[1]); o[2] = f2bf(v[2]); o[3] = f2bf(v[3]);
  ((u16x4*)out)[i] = o;
}

// -------- transpose-cast: src f32 [K][N] -> dst bf16 [N][K] --------
__global__ __launch_bounds__(256) void k_tcast(const float* __restrict__ src,
                                               unsigned short* __restrict__ dst,
                                               int K, int N) {
  __shared__ float tile[32][33];
  int gx = blockIdx.x * 32;  // N dim
  int gy = blockIdx.y * 32;  // K dim
  int t = threadIdx.x;
  int c = t & 31, r0 = t >> 5;
#pragma unroll
  for (int i = 0; i < 4; i++) {
    int r = r0 + i * 8;
    tile[r][c] = src[(size_t)(gy + r) * N + gx + c];
  }
  __syncthreads();
#pragma unroll
  for (int i = 0; i < 4; i++) {
    int r = r0 + i * 8;
    dst[(size_t)(gx + r) * K + gy + c] = f2bf(tile[c][r]);
  }
}

// ---- folded bias: out[n] = bv[n] + sum_j bk[j]*wv[j][n]  (f32, 1024 wide) ----
__global__ __launch_bounds__(256) void k_bfold(const float* __restrict__ bk,
                                               const float* __restrict__ wv,
                                               const float* __restrict__ bv,
                                               float* __restrict__ out) {
  int n = blockIdx.x * 256 + threadIdx.x;
  float acc = bv[n];
#pragma unroll 8
  for (int j = 0; j < 1024; j++) acc += bk[j] * wv[(size_t)j * 1024 + n];
  out[n] = acc;
}

// ---- concat two 1024-f32 vectors into out[0..2047] ----
__global__ __launch_bounds__(256) void k_cpb(const float* __restrict__ a,
                                             const float* __restrict__ b,
                                             float* __restrict__ out) {
  int t = blockIdx.x * 256 + threadIdx.x;
  out[t] = a[t];
  out[1024 + t] = b[t];
}

// ======== 8-phase-family MFMA GEMM (m201 template adapted): 256x256 tile, BK=64 ========
// C[M][N] = A[M][K](bf16 rm) * Bt[N][K]^T + bias (opt exact GELU).
// 512 threads = 8 waves (2m x 4n); wave tile 128x64; acc 8x4 f32x4 (128 AGPR).
// LDS: 2 double-buffered 256x64 tiles for A and B = 128 KiB (1 block/CU).
// Per K-tile (K=64): 4 phases, each {ds_read subtile; [stage]; BAR; setprio(1);
// 16 MFMA (one C-quadrant); setprio(0); BAR}. Stage of tile j+1: 4 A-loads in phase 0,
// 4 B-loads in phase 1 (>=2.5-phase lead). vmcnt(0) ONLY at tile boundary (pre-barrier;
// loads had ~3 phases to land). T2 swizzle for 128B rows: LDS linear, global source
// chunk = (l&7)^((l>>3)&7); read chunk = (ks*4+g)^(ra&7).  Races checked: stages target
// buf^1 whose readers passed the previous tile-boundary barrier; Ep scratch (As[0]) only
// touched after final barrier, last tile reads As[1] (NT even for K=1024/4096).
template <bool GELU>
__global__ __launch_bounds__(512, 2) void k_gemm8(const unsigned short* __restrict__ A,
                                                  const unsigned short* __restrict__ Bt,
                                                  const float* __restrict__ bias,
                                                  unsigned short* __restrict__ C,
                                                  int M, int N, int K) {
  __shared__ unsigned short As[2][256 * 64];
  __shared__ unsigned short Bs[2][256 * 64];
  const int rowA0 = blockIdx.y * 256, colB0 = blockIdx.x * 256;
  const int t = threadIdx.x, w = t >> 6, lane = t & 63;
  const int wm = w >> 2, wn = w & 3;
  const int g = lane >> 4, ra = lane & 15;
  // T2 read-side: logical 16B-chunk c16 = ks*4+g, physical = c16 ^ (ra&7)
  const int koff0 = (((0 * 4 + g) ^ (ra & 7)) * 8);
  const int koff1 = (((1 * 4 + g) ^ (ra & 7)) * 8);
  // staging: 8 rows/wave per instr; source chunk pre-swizzled (inverse of read XOR)
  const int srow = w * 8 + (lane >> 3);
  const int schunk = ((lane & 7) ^ ((lane >> 3) & 7)) * 8;

  f32x4 acc[8][4] = {};

  auto stageA = [&](int buf, int kk) {
#pragma unroll
    for (int gq = 0; gq < 4; gq++)
      gl2lds16(A + (size_t)(rowA0 + gq * 64 + srow) * K + kk + schunk,
               &As[buf][gq * 4096 + w * 512]);
  };
  auto stageB = [&](int buf, int kk) {
#pragma unroll
    for (int gq = 0; gq < 4; gq++)
      gl2lds16(Bt + (size_t)(colB0 + gq * 64 + srow) * K + kk + schunk,
               &Bs[buf][gq * 4096 + w * 512]);
  };

  const int NT = K >> 6;
  stageA(0, 0); stageB(0, 0);
  asm volatile("s_waitcnt vmcnt(0)" ::: "memory");
  __builtin_amdgcn_sched_barrier(0);
  __builtin_amdgcn_s_barrier();

  bf16x8 aH[4][2], bH[2][2][2];
  const int arow0 = wm * 128, brow0 = wn * 64;
  for (int j = 0; j < NT; ++j) {
    const int buf = j & 1;
    const unsigned short* Ab = &As[buf][0];
    const unsigned short* Bb = &Bs[buf][0];
    // ---------- phase 0: read A-half0 + B-half0; stage A(j+1); MFMA quad(0,0)
#pragma unroll
    for (int fr = 0; fr < 4; fr++) {
      aH[fr][0] = *(const bf16x8*)&Ab[(arow0 + fr * 16 + ra) * 64 + koff0];
      aH[fr][1] = *(const bf16x8*)&Ab[(arow0 + fr * 16 + ra) * 64 + koff1];
    }
#pragma unroll
    for (int fc = 0; fc < 2; fc++) {
      bH[0][fc][0] = *(const bf16x8*)&Bb[(brow0 + fc * 16 + ra) * 64 + koff0];
      bH[0][fc][1] = *(const bf16x8*)&Bb[(brow0 + fc * 16 + ra) * 64 + koff1];
    }
    if (j + 1 < NT) stageA(buf ^ 1, (j + 1) << 6);
    __builtin_amdgcn_sched_barrier(0);
    __builtin_amdgcn_s_barrier();
    __builtin_amdgcn_sched_barrier(0);
    __builtin_amdgcn_s_setprio(1);
#pragma unroll
    for (int fr = 0; fr < 4; fr++)
#pragma unroll
      for (int fc = 0; fc < 2; fc++)
#pragma unroll
        for (int ks = 0; ks < 2; ks++)
          acc[fr][fc] = __builtin_amdgcn_mfma_f32_16x16x32_bf16(aH[fr][ks], bH[0][fc][ks], acc[fr][fc], 0, 0, 0);
    __builtin_amdgcn_s_setprio(0);
    __builtin_amdgcn_sched_barrier(0);
    __builtin_amdgcn_s_barrier();
    // ---------- phase 1: read B-half1; stage B(j+1); MFMA quad(0,1)
#pragma unroll
    for (int fc = 0; fc < 2; fc++) {
      bH[1][fc][0] = *(const bf16x8*)&Bb[(brow0 + 32 + fc * 16 + ra) * 64 + koff0];
      bH[1][fc][1] = *(const bf16x8*)&Bb[(brow0 + 32 + fc * 16 + ra) * 64 + koff1];
    }
    if (j + 1 < NT) stageB(buf ^ 1, (j + 1) << 6);
    __builtin_amdgcn_sched_barrier(0);
    __builtin_amdgcn_s_barrier();
    __builtin_amdgcn_sched_barrier(0);
    __builtin_amdgcn_s_setprio(1);
#pragma unroll
    for (int fr = 0; fr < 4; fr++)
#pragma unroll
      for (int fc = 0; fc < 2; fc++)
#pragma unroll
        for (int ks = 0; ks < 2; ks++)
          acc[fr][2 + fc] = __builtin_amdgcn_mfma_f32_16x16x32_bf16(aH[fr][ks], bH[1][fc][ks], acc[fr][2 + fc], 0, 0, 0);
    __builtin_amdgcn_s_setprio(0);
    __builtin_amdgcn_sched_barrier(0);
    __builtin_amdgcn_s_barrier();
    // ---------- phase 2: read A-half1; MFMA quad(1,0)
#pragma unroll
    for (int fr = 0; fr < 4; fr++) {
      aH[fr][0] = *(const bf16x8*)&Ab[(arow0 + 64 + fr * 16 + ra) * 64 + koff0];
      aH[fr][1] = *(const bf16x8*)&Ab[(arow0 + 64 + fr * 16 + ra) * 64 + koff1];
    }
    __builtin_amdgcn_sched_barrier(0);
    __builtin_amdgcn_s_barrier();
    __builtin_amdgcn_sched_barrier(0);
    __builtin_amdgcn_s_setprio(1);
#pragma unroll
    for (int fr = 0; fr < 4; fr++)
#pragma unroll
      for (int fc = 0; fc < 2; fc++)
#pragma unroll
        for (int ks = 0; ks < 2; ks++)
          acc[4 + fr][fc] = __builtin_amdgcn_mfma_f32_16x16x32_bf16(aH[fr][ks], bH[0][fc][ks], acc[4 + fr][fc], 0, 0, 0);
    __builtin_amdgcn_s_setprio(0);
    __builtin_amdgcn_sched_barrier(0);
    __builtin_amdgcn_s_barrier();
    // ---------- phase 3: MFMA quad(1,1); tile-boundary counted wait (pre-barrier)
    __builtin_amdgcn_s_setprio(1);
#pragma unroll
    for (int fr = 0; fr < 4; fr++)
#pragma unroll
      for (int fc = 0; fc < 2; fc++)
#pragma unroll
        for (int ks = 0; ks < 2; ks++)
          acc[4 + fr][2 + fc] = __builtin_amdgcn_mfma_f32_16x16x32_bf16(aH[fr][ks], bH[1][fc][ks], acc[4 + fr][2 + fc], 0, 0, 0);
    __builtin_amdgcn_s_setprio(0);
    if (j + 1 < NT) asm volatile("s_waitcnt vmcnt(0)" ::: "memory");  // j+1 loads: ~3 phases lead
    __builtin_amdgcn_sched_barrier(0);
    __builtin_amdgcn_s_barrier();
  }

  // ---- epilogue: per-wave LDS transpose (XOR-swizzled), 16B coalesced stores ----
  unsigned short* Ep = &As[0][0] + w * 1024;  // 16x64 u16 per wave; last tile read As[1]
  const int grow0 = rowA0 + wm * 128;
  const int gcol0 = colB0 + wn * 64;
  float bv[4];
#pragma unroll
  for (int n = 0; n < 4; n++) bv[n] = bias ? bias[gcol0 + n * 16 + ra] : 0.f;
  const int rdrow = lane >> 3, rg = lane & 7;
#pragma unroll
  for (int m = 0; m < 8; m++) {
#pragma unroll
    for (int n = 0; n < 4; n++)
#pragma unroll
      for (int i = 0; i < 4; i++) {
        int r = g * 4 + i;
        float v = acc[m][n][i] + bv[n];
        if (GELU) v = 0.5f * v * (1.f + erff(v * 0.70710678118654752f));
        Ep[r * 64 + ((ra + n * 16) ^ ((r & 7) << 3))] = f2bf(v);
      }
    asm volatile("s_waitcnt lgkmcnt(0)" ::: "memory");
    __builtin_amdgcn_sched_barrier(0);
#pragma unroll
    for (int p = 0; p < 2; p++) {
      int rr = p * 8 + rdrow;
      bf16x8 val = *(const bf16x8*)&Ep[rr * 64 + ((rg ^ (rr & 7)) << 3)];
      *(bf16x8*)&C[(size_t)(grow0 + m * 16 + rr) * N + gcol0 + rg * 8] = val;
    }
    asm volatile("s_waitcnt lgkmcnt(0)" ::: "memory");
  }
}

// ======== small MFMA GEMM (folds, 1024^3): 128^2 tile, ring-3 (round-9 proven) ========
__global__ __launch_bounds__(256) void k_gemmS(const unsigned short* __restrict__ A,
                                               const unsigned short* __restrict__ Bt,
                                               const float* __restrict__ bias,
                                               unsigned short* __restrict__ C,
                                               int M, int N, int K) {
  __shared__ unsigned short As[3][128 * 32];
  __shared__ unsigned short Bs[3][128 * 32];
  const int rowA0 = blockIdx.y * 128, colB0 = blockIdx.x * 128;
  const int t = threadIdx.x, w = t >> 6, lane = t & 63;
  const int wr = w >> 1, wc = w & 1;
  const int srow = w * 16 + (lane >> 2);
  const int schunk = (lane & 3) ^ ((lane >> 3) & 3);
  const unsigned short* pa = A + (size_t)(rowA0 + srow) * K + schunk * 8;
  const unsigned short* pb = Bt + (size_t)(colB0 + srow) * K + schunk * 8;
  const size_t row64 = (size_t)64 * K;
  f32x4 acc[4][4] = {};
  const int g = lane >> 4, ra = lane & 15;
  const int gp8 = (g ^ ((ra >> 1) & 3)) * 8;
  auto stage = [&](int buf, int kk) {
    gl2lds16(pa + kk, &As[buf][w * 512]);
    gl2lds16(pa + row64 + kk, &As[buf][2048 + w * 512]);
    gl2lds16(pb + kk, &Bs[buf][w * 512]);
    gl2lds16(pb + row64 + kk, &Bs[buf][2048 + w * 512]);
  };
  const int NT = K >> 5;
  stage(0, 0);
  if (NT > 1) stage(1, 32);
  int cur = 0;
  for (int j = 0; j < NT; ++j) {
    if (j + 1 < NT) asm volatile("s_waitcnt vmcnt(4)" ::: "memory");
    else            asm volatile("s_waitcnt vmcnt(0)" ::: "memory");
    __syncthreads();
    if (j + 2 < NT) { int nb = cur + 2; if (nb >= 3) nb -= 3; stage(nb, (j + 2) * 32); }
    bf16x8 af[4], bfr[4];
#pragma unroll
    for (int m = 0; m < 4; m++)
      af[m] = *(const bf16x8*)&As[cur][(wr * 64 + m * 16 + ra) * 32 + gp8];
#pragma unroll
    for (int n = 0; n < 4; n++)
      bfr[n] = *(const bf16x8*)&Bs[cur][(wc * 64 + n * 16 + ra) * 32 + gp8];
#pragma unroll
    for (int m = 0; m < 4; m++)
#pragma unroll
      for (int n = 0; n < 4; n++)
        acc[m][n] = __builtin_amdgcn_mfma_f32_16x16x32_bf16(af[m], bfr[n], acc[m][n], 0, 0, 0);
    __syncthreads();
    cur += 1; if (cur >= 3) cur -= 3;
  }
  const int cr = g * 4, cc = ra;
#pragma unroll
  for (int m = 0; m < 4; m++) {
    int grow = rowA0 + wr * 64 + m * 16 + cr;
#pragma unroll
    for (int n = 0; n < 4; n++) {
      int gcol = colB0 + wc * 64 + n * 16 + cc;
      float bvv = bias ? bias[gcol] : 0.f;
#pragma unroll
      for (int i = 0; i < 4; i++)
        C[(size_t)(grow + i) * N + gcol] = f2bf(acc[m][n][i] + bvv);
    }
  }
}

// ---------------- small GEMM (M<=10): C[Mr][1024] = A[Mr][1024] * Wt^T + bias ----------------
__global__ __launch_bounds__(256) void k_gemm10(const unsigned short* __restrict__ A,
                                                const unsigned short* __restrict__ Bt,
                                                const float* __restrict__ bias,
                                                unsigned short* __restrict__ C) {
  __shared__ float af[1024];
  int m = blockIdx.x, nb = blockIdx.y;
  int t = threadIdx.x;
#pragma unroll
  for (int i = 0; i < 4; i++) af[t * 4 + i] = bf2f(A[(size_t)m * 1024 + t * 4 + i]);
  __syncthreads();
  int w = t >> 6, lane = t & 63;
  for (int n = nb * 64 + w; n < nb * 64 + 64; n += 4) {
    const unsigned short* brow = Bt + (size_t)n * 1024 + lane * 16;
    float acc = 0.f;
#pragma unroll
    for (int j = 0; j < 16; j++) acc += af[lane * 16 + j] * bf2f(brow[j]);
#pragma unroll
    for (int o = 32; o; o >>= 1) acc += __shfl_xor(acc, o);
    if (lane == 0) C[(size_t)m * 1024 + n] = f2bf(acc + bias[n]);
  }
}

// ---------------- entmax-1.5 attention, MFMA version (RS = input row stride) ----------------
template <int L, int S, bool SHARED>
__global__ __launch_bounds__(256) void k_attn(const unsigned short* __restrict__ Q,
                                              const unsigned short* __restrict__ Kb,
                                              const unsigned short* __restrict__ Vb,
                                              unsigned short* __restrict__ Out, int RS) {
  constexpr int SP = (S <= 32) ? 32 : 64;
  constexpr int QST = 72;
  constexpr int VST = SP + 8;
  constexpr int CST = SP + 4;
  __shared__ unsigned short Qs[L * QST];
  __shared__ unsigned short Ks[SP * QST];
  __shared__ unsigned short Vt[64 * VST];
  __shared__ float Sc[L * CST];
  __shared__ float Rps[L];
  const int blk = blockIdx.x, batch = blk >> 4, h = blk & 15;
  const int t = threadIdx.x, w = t >> 6, lane = t & 63;
  for (int c = t; c < L * 8; c += 256) {
    int r = c >> 3, ch = (c & 7) * 8;
    *(i32x4*)&Qs[r * QST + ch] =
        *(const i32x4*)&Q[((size_t)(batch * L + r)) * RS + h * 64 + ch];
  }
  for (int c = t; c < SP * 8; c += 256) {
    int r = c >> 3, ch = (c & 7) * 8;
    i32x4 v = {0, 0, 0, 0};
    if (r < S) {
      size_t rb = SHARED ? (size_t)r : (size_t)(batch * S + r);
      v = *(const i32x4*)&Kb[rb * RS + h * 64 + ch];
    }
    *(i32x4*)&Ks[r * QST + ch] = v;
  }
  for (int c = t; c < SP * 64; c += 256) {
    int s = c >> 6, e = c & 63;
    unsigned short v = 0;
    if (s < S) {
      size_t rb = SHARED ? (size_t)s : (size_t)(batch * S + s);
      v = Vb[rb * RS + h * 64 + e];
    }
    Vt[e * VST + s] = v;
  }
  __syncthreads();
  const int ka = (lane >> 4) * 8, ra = lane & 15;
  const int cr = (lane >> 4) * 4, cc = lane & 15;
  constexpr int NT = SP / 16, TT = (L / 16) * NT;
  for (int tt = w; tt < TT; tt += 4) {
    int m = tt / NT, n = tt % NT;
    f32x4 a = {0.f, 0.f, 0.f, 0.f};
#pragma unroll
    for (int ks = 0; ks < 2; ks++) {
      bf16x8 af = *(const bf16x8*)&Qs[(m * 16 + ra) * QST + ks * 32 + ka];
      bf16x8 bf = *(const bf16x8*)&Ks[(n * 16 + ra) * QST + ks * 32 + ka];
      a = __builtin_amdgcn_mfma_f32_16x16x32_bf16(af, bf, a, 0, 0, 0);
    }
#pragma unroll
    for (int i = 0; i < 4; i++)
      Sc[(m * 16 + cr + i) * CST + n * 16 + cc] = a[i] * 0.0625f;
  }
  __syncthreads();
  constexpr int G = 256 / L, RW = 64 / G, SL = SP / G;
  const int row = w * RW + lane / G, sub = lane % G;
  float xs[SL];
#pragma unroll
  for (int j = 0; j < SL; j++) {
    int s = sub * SL + j;
    float v = Sc[row * CST + s];
    if (S < SP && s >= S) v = -1e30f;
    xs[j] = v;
  }
  float mx = xs[0];
#pragma unroll
  for (int j = 1; j < SL; j++) mx = fmaxf(mx, xs[j]);
#pragma unroll
  for (int o = G / 2; o; o >>= 1) mx = fmaxf(mx, __shfl_xor(mx, o));
  const float hoff = (S == 64) ? 0.125f : (S == 32) ? 0.17677669529663687f : 0.31622776601683794f;
  float lo = mx - 1.f, hi = mx - hoff;
#pragma unroll 1
  for (int it = 0; it < 26; it++) {
    float mid = 0.5f * (lo + hi);
    float f = 0.f;
#pragma unroll
    for (int j = 0; j < SL; j++) { float dd = fmaxf(xs[j] - mid, 0.f); f += dd * dd; }
#pragma unroll
    for (int o = G / 2; o; o >>= 1) f += __shfl_xor(f, o);
    bool gt = f > 1.f;
    lo = gt ? mid : lo;
    hi = gt ? hi : mid;
  }
  float tau = 0.5f * (lo + hi);
  float ps = 0.f;
#pragma unroll
  for (int j = 0; j < SL; j++) { float dd = fmaxf(xs[j] - tau, 0.f); xs[j] = dd * dd; ps += xs[j]; }
#pragma unroll
  for (int o = G / 2; o; o >>= 1) ps += __shfl_xor(ps, o);
  if (sub == 0) Rps[row] = 1.f / ps;
  unsigned short* Pb = Qs;
#pragma unroll
  for (int j = 0; j < SL; j += 4) {
    u16x4 pv;
#pragma unroll
    for (int jj = 0; jj < 4; jj++) pv[jj] = f2bf(xs[j + jj]);
    *(u16x4*)&Pb[row * VST + sub * SL + j] = pv;
  }
  __syncthreads();
  constexpr int TT2 = (L / 16) * 4;
  for (int tt = w; tt < TT2; tt += 4) {
    int m = tt >> 2, n = tt & 3;
    f32x4 a = {0.f, 0.f, 0.f, 0.f};
#pragma unroll
    for (int ks = 0; ks < SP / 32; ks++) {
      bf16x8 af = *(const bf16x8*)&Pb[(m * 16 + ra) * VST + ks * 32 + ka];
      bf16x8 bf = *(const bf16x8*)&Vt[(n * 16 + ra) * VST + ks * 32 + ka];
      a = __builtin_amdgcn_mfma_f32_16x16x32_bf16(af, bf, a, 0, 0, 0);
    }
#pragma unroll
    for (int i = 0; i < 4; i++) {
      int l = m * 16 + cr + i, e = n * 16 + cc;
      float val = a[i] * Rps[l];
      int l_new = h * (L / 16) + (l >> 4);
      int cg = (l & 15) * 64 + e;
      Out[((size_t)(batch * L + l_new)) * 1024 + cg] = f2bf(val);
    }
  }
}

// ---------------- LayerNorm(a+b) * g + be, optional row permutation / f32 out ----------------
template <int MODE, bool F32OUT>
__global__ __launch_bounds__(256) void k_ln(const unsigned short* __restrict__ a,
                                            const unsigned short* __restrict__ b,
                                            const float* __restrict__ g,
                                            const float* __restrict__ be,
                                            void* __restrict__ outp) {
  __shared__ float red[8];
  int r = blockIdx.x, t = threadIdx.x;
  size_t base = (size_t)r * 1024 + t * 4;
  u16x4 av = *(const u16x4*)(a + base);
  u16x4 bv = *(const u16x4*)(b + base);
  float x[4];
  float s = 0.f, ss = 0.f;
#pragma unroll
  for (int i = 0; i < 4; i++) {
    x[i] = bf2f(av[i]) + bf2f(bv[i]);
    s += x[i]; ss += x[i] * x[i];
  }
#pragma unroll
  for (int o = 32; o; o >>= 1) { s += __shfl_xor(s, o); ss += __shfl_xor(ss, o); }
  int w = t >> 6;
  if ((t & 63) == 0) { red[w] = s; red[4 + w] = ss; }
  __syncthreads();
  s = red[0] + red[1] + red[2] + red[3];
  ss = red[4] + red[5] + red[6] + red[7];
  float mean = s * (1.f / 1024.f);
  float var = ss * (1.f / 1024.f) - mean * mean;
  float rstd = rsqrtf(var + 1e-5f);
  int orow;
  if (MODE == 0) orow = r;
  else if (MODE == 1) { int bi = r >> 11, rem = r & 2047; int tt = rem >> 6, sd = rem & 63; orow = (bi << 11) + sd * 32 + tt; }
  else { int bi = r >> 11, rem = r & 2047; int sd = rem >> 5, tt = rem & 31; orow = (bi << 11) + tt * 64 + sd; }
  size_t ob = (size_t)orow * 1024 + t * 4;
  if (F32OUT) {
    f32x4 y;
#pragma unroll
    for (int i = 0; i < 4; i++) y[i] = (x[i] - mean) * rstd * g[t * 4 + i] + be[t * 4 + i];
    *(f32x4*)((float*)outp + ob) = y;
  } else {
    u16x4 y;
#pragma unroll
    for (int i = 0; i < 4; i++) y[i] = f2bf((x[i] - mean) * rstd * g[t * 4 + i] + be[t * 4 + i]);
    *(u16x4*)((unsigned short*)outp + ob) = y;
  }
}

// =======================================================================================

extern "C" void kernel_launch(void* const* d_in, const int* in_sizes, int n_in,
                              void* d_out, int out_size, void* d_ws, size_t ws_size,
                              hipStream_t stream) {
  const int M = 16384;
  if (n_in < 43 || in_sizes[0] != 16777216 || in_sizes[25] != 10240 || in_sizes[34] != 4194304) {
    fprintf(stderr, "kernel_launch: unexpected input layout (n_in=%d)\n", n_in);
    return;
  }
  const float* x = (const float*)d_in[0];
  const float* w[3][4]; const float* bia[3][4];
  for (int p = 0; p < 3; p++) {
    w[p][0] = (const float*)d_in[1 + 8 * p + 0]; bia[p][0] = (const float*)d_in[1 + 8 * p + 1];
    w[p][1] = (const float*)d_in[1 + 8 * p + 2]; bia[p][1] = (const float*)d_in[1 + 8 * p + 3];
    w[p][2] = (const float*)d_in[1 + 8 * p + 4]; bia[p][2] = (const float*)d_in[1 + 8 * p + 5];
    w[p][3] = (const float*)d_in[1 + 8 * p + 6]; bia[p][3] = (const float*)d_in[1 + 8 * p + 7];
  }
  const float* cs_key = (const float*)d_in[25];
  const float* ng[4]; const float* nb[4];
  for (int i = 0; i < 4; i++) { ng[i] = (const float*)d_in[26 + 2 * i]; nb[i] = (const float*)d_in[27 + 2 * i]; }
  const float* m_w1[2]; const float* m_b1[2]; const float* m_w2[2]; const float* m_b2[2];
  for (int i = 0; i < 2; i++) {
    m_w1[i] = (const float*)d_in[34 + 4 * i]; m_b1[i] = (const float*)d_in[35 + 4 * i];
    m_w2[i] = (const float*)d_in[36 + 4 * i]; m_b2[i] = (const float*)d_in[37 + 4 * i];
  }

  // ---- workspace: weights ~56 MiB + 6 x 32 MiB activation slots = ~248 MiB ----
  char* base = (char*)d_ws; size_t off = 0;
  auto alloc = [&](size_t bytes) -> void* {
    off = (off + 255) & ~(size_t)255;
    void* p = base + off; off += bytes; return p;
  };
  const size_t W1M = (size_t)1024 * 1024;
  unsigned short* W3ct = (unsigned short*)alloc(3 * W1M * 2);  // [wqT; wkT; wkvT]
  unsigned short* W3hp = (unsigned short*)alloc(3 * W1M * 2);
  unsigned short* Woct = (unsigned short*)alloc(W1M * 2);
  unsigned short* Wohp = (unsigned short*)alloc(W1M * 2);
  unsigned short* Wocs = (unsigned short*)alloc(W1M * 2);
  unsigned short* Wqcs = (unsigned short*)alloc(W1M * 2);
  unsigned short* Wkcs = (unsigned short*)alloc(W1M * 2);
  unsigned short* Wvcs = (unsigned short*)alloc(W1M * 2);
  unsigned short* Wm1u = (unsigned short*)alloc((size_t)4096 * 1024 * 2);
  unsigned short* Wm1d = (unsigned short*)alloc((size_t)1024 * 4096 * 2);
  unsigned short* Wm2u = (unsigned short*)alloc((size_t)4096 * 1024 * 2);
  unsigned short* Wm2d = (unsigned short*)alloc((size_t)1024 * 4096 * 2);
  float* b3ct = (float*)alloc(3072 * 4);
  float* b3hp = (float*)alloc(3072 * 4);
  unsigned short* KeyB = (unsigned short*)alloc((size_t)10 * 1024 * 2);
  unsigned short* Kcs = (unsigned short*)alloc((size_t)10 * 1024 * 2);
  unsigned short* Vcs = (unsigned short*)alloc((size_t)10 * 1024 * 2);
  unsigned short* S[6];
  for (int i = 0; i < 6; i++) S[i] = (unsigned short*)alloc((size_t)M * 1024 * 2);
  if (off > ws_size) {
    fprintf(stderr, "kernel_launch: ws too small: need %zu have %zu\n", off, ws_size);
    return;
  }
  // fold scratch aliased into S1 (dead during prep)
  unsigned short* Wvt_ct = S[1];
  unsigned short* Wraw_ct = S[1] + W1M;
  unsigned short* Wvt_hp = S[1] + 2 * W1M;
  unsigned short* Wraw_hp = S[1] + 3 * W1M;

  auto gemm = [&](const unsigned short* Ap, const unsigned short* Bt, const float* bi,
                  unsigned short* Cp, int Mm, int Nn, int Kk, bool gelu) {
    dim3 gg(Nn / 256, Mm / 256);
    if (gelu) k_gemm8<true><<<gg, 512, 0, stream>>>(Ap, Bt, bi, Cp, Mm, Nn, Kk);
    else      k_gemm8<false><<<gg, 512, 0, stream>>>(Ap, Bt, bi, Cp, Mm, Nn, Kk);
  };
  auto tc = [&](const float* src, unsigned short* dst) {
    k_tcast<<<dim3(32, 32), 256, 0, stream>>>(src, dst, 1024, 1024);
  };

  // ---- weight prep ----
  tc(w[0][0], W3ct); tc(w[0][1], W3ct + W1M);
  tc(w[2][0], W3hp); tc(w[2][1], W3hp + W1M);
  tc(w[0][3], Woct); tc(w[2][3], Wohp); tc(w[1][3], Wocs);
  tc(w[1][0], Wqcs); tc(w[1][1], Wkcs); tc(w[1][2], Wvcs);
  k_tcast<<<dim3(128, 32), 256, 0, stream>>>(m_w1[0], Wm1u, 1024, 4096);
  k_tcast<<<dim3(32, 128), 256, 0, stream>>>(m_w2[0], Wm1d, 4096, 1024);
  k_tcast<<<dim3(128, 32), 256, 0, stream>>>(m_w1[1], Wm2u, 1024, 4096);
  k_tcast<<<dim3(32, 128), 256, 0, stream>>>(m_w2[1], Wm2d, 4096, 1024);
  tc(w[0][2], Wvt_ct); k_cast<<<1024, 256, 0, stream>>>(w[0][1], Wraw_ct, 262144);
  tc(w[2][2], Wvt_hp); k_cast<<<1024, 256, 0, stream>>>(w[2][1], Wraw_hp, 262144);
  k_cast<<<16384, 256, 0, stream>>>(x, S[0], 16777216 / 4);
  k_cast<<<10, 256, 0, stream>>>(cs_key, KeyB, 10240 / 4);
  // folded V weights (1024^3 via the small-tile kernel)
  k_gemmS<<<dim3(8, 8), 256, 0, stream>>>(Wvt_ct, Wraw_ct, nullptr, W3ct + 2 * W1M, 1024, 1024, 1024);
  k_gemmS<<<dim3(8, 8), 256, 0, stream>>>(Wvt_hp, Wraw_hp, nullptr, W3hp + 2 * W1M, 1024, 1024, 1024);
  // folded biases
  k_cpb<<<4, 256, 0, stream>>>(bia[0][0], bia[0][1], b3ct);
  k_bfold<<<4, 256, 0, stream>>>(bia[0][1], w[0][2], bia[0][2], b3ct + 2048);
  k_cpb<<<4, 256, 0, stream>>>(bia[2][0], bia[2][1], b3hp);
  k_bfold<<<4, 256, 0, stream>>>(bia[2][1], w[2][2], bia[2][2], b3hp + 2048);
  k_gemm10<<<dim3(10, 16), 256, 0, stream>>>(KeyB, Wkcs, bia[1][1], Kcs);
  k_gemm10<<<dim3(10, 16), 256, 0, stream>>>(Kcs, Wvcs, bia[1][2], Vcs);

  // ---- stage T (L=S=64 attention over seg) ----
  gemm(S[0], W3ct, b3ct, S[1], M, 3072, 1024, false);                       // QKV -> S1..S3
  k_attn<64, 64, false><<<256 * 16, 256, 0, stream>>>(S[1], S[1] + 1024, S[1] + 2048, S[4], 3072);
  gemm(S[4], Woct, bia[0][3], S[5], M, 1024, 1024, false);                  // enc -> S5
  k_ln<0, false><<<M, 256, 0, stream>>>(S[0], S[5], ng[0], nb[0], S[1]);    // D -> S1
  gemm(S[1], Wm1u, m_b1[0], S[2], M, 4096, 1024, true);                     // H -> S2..S5
  gemm(S[2], Wm1d, m_b2[0], S[0], M, 1024, 4096, false);                    // R -> S0
  k_ln<1, false><<<M, 256, 0, stream>>>(S[1], S[0], ng[1], nb[1], S[2]);    // S_in -> S2 (permuted)

  // ---- stage S (L=32) ----
  gemm(S[2], W3hp, b3hp, S[3], M, 3072, 1024, false);                       // QKVhp -> S3..S5
  k_attn<32, 32, false><<<512 * 16, 256, 0, stream>>>(S[3], S[3] + 1024, S[3] + 2048, S[0], 3072);
  gemm(S[0], Wohp, bia[2][3], S[1], M, 1024, 1024, false);                  // PH -> S1
  gemm(S[2], Wqcs, bia[1][0], S[3], M, 1024, 1024, false);                  // Qcs -> S3
  k_attn<32, 10, true><<<512 * 16, 256, 0, stream>>>(S[3], Kcs, Vcs, S[4], 1024);
  gemm(S[4], Wocs, bia[1][3], S[5], M, 1024, 1024, false);                  // SH -> S5
  k_ln<0, false><<<M, 256, 0, stream>>>(S[5], S[1], ng[2], nb[2], S[0]);    // DE -> S0
  gemm(S[0], Wm2u, m_b1[1], S[1], M, 4096, 1024, true);                     // H -> S1..S4
  gemm(S[1], Wm2d, m_b2[1], S[5], M, 1024, 4096, false);                    // R2 -> S5
  k_ln<2, true><<<M, 256, 0, stream>>>(S[0], S[5], ng[3], nb[3], d_out);    // final LN+permute f32
}

// Round 11
// 1603.641 us; speedup vs baseline: 1.1466x; 1.0419x over previous
//
#include <hip/hip_runtime.h>
#include <cstdio>

typedef __bf16 bf16x8 __attribute__((ext_vector_type(8)));
typedef float f32x4 __attribute__((ext_vector_type(4)));
typedef int i32x4 __attribute__((ext_vector_type(4)));
typedef unsigned short u16x4 __attribute__((ext_vector_type(4)));

__device__ __forceinline__ float bf2f(unsigned short u) {
  union { unsigned int i; float f; } x; x.i = ((unsigned int)u) << 16; return x.f;
}
__device__ __forceinline__ unsigned short f2bf(float f) {
  union { float f; unsigned int i; } x; x.f = f;
  unsigned int r = x.i + 0x7fffu + ((x.i >> 16) & 1u);
  return (unsigned short)(r >> 16);
}

// async global->LDS, 16B per lane; LDS dest is wave-uniform base + lane*16
__device__ __forceinline__ void gl2lds16(const unsigned short* g, unsigned short* l) {
  __builtin_amdgcn_global_load_lds((const __attribute__((address_space(1))) unsigned int*)g,
                                   (__attribute__((address_space(3))) unsigned int*)l, 16, 0, 0);
}

// ---------------- elementwise f32 -> bf16 cast (vec4) ----------------
__global__ __launch_bounds__(256) void k_cast(const float* __restrict__ in,
                                              unsigned short* __restrict__ out, int n4) {
  int i = blockIdx.x * 256 + threadIdx.x;
  if (i >= n4) return;
  f32x4 v = ((const f32x4*)in)[i];
  u16x4 o;
  o[0] = f2bf(v[0]); o[1] = f2bf(v[1]); o[2] = f2bf(v[2]); o[3] = f2bf(v[3]);
  ((u16x4*)out)[i] = o;
}

// -------- transpose-cast: src f32 [K][N] -> dst bf16 [N][K] --------
__global__ __launch_bounds__(256) void k_tcast(const float* __restrict__ src,
                                               unsigned short* __restrict__ dst,
                                               int K, int N) {
  __shared__ float tile[32][33];
  int gx = blockIdx.x * 32;  // N dim
  int gy = blockIdx.y * 32;  // K dim
  int t = threadIdx.x;
  int c = t & 31, r0 = t >> 5;
#pragma unroll
  for (int i = 0; i < 4; i++) {
    int r = r0 + i * 8;
    tile[r][c] = src[(size_t)(gy + r) * N + gx + c];
  }
  __syncthreads();
#pragma unroll
  for (int i = 0; i < 4; i++) {
    int r = r0 + i * 8;
    dst[(size_t)(gx + r) * K + gy + c] = f2bf(tile[c][r]);
  }
}

// ---- folded bias: out[n] = bv[n] + sum_j bk[j]*wv[j][n]  (f32, 1024 wide) ----
__global__ __launch_bounds__(256) void k_bfold(const float* __restrict__ bk,
                                               const float* __restrict__ wv,
                                               const float* __restrict__ bv,
                                               float* __restrict__ out) {
  int n = blockIdx.x * 256 + threadIdx.x;
  float acc = bv[n];
#pragma unroll 8
  for (int j = 0; j < 1024; j++) acc += bk[j] * wv[(size_t)j * 1024 + n];
  out[n] = acc;
}

// ---- concat two 1024-f32 vectors into out[0..2047] ----
__global__ __launch_bounds__(256) void k_cpb(const float* __restrict__ a,
                                             const float* __restrict__ b,
                                             float* __restrict__ out) {
  int t = blockIdx.x * 256 + threadIdx.x;
  out[t] = a[t];
  out[1024 + t] = b[t];
}

// ======== 8-phase-family MFMA GEMM, TRUE counted vmcnt (r11): 256x256 tile, BK=64 ========
// C[M][N] = A[M][K](bf16 rm) * Bt[N][K]^T + bias (opt exact GELU).
// 512 threads = 8 waves (2m x 4n); wave tile 128x64; acc 8x4 f32x4.
// LDS: 2 double-buffered 256x64 tiles (A,B) = 128 KiB.
// Pipeline (the r11 fix): stage tile j+2 into buf(j&1) LATE in tile j —
//   B(j+2) at phase 2 (B(j) reads forced complete before phase-1's closing barrier),
//   A(j+2) at phase 3 (A(j) reads complete before phase-2's closing barrier).
// Boundary wait = vmcnt(8): A(j+1),B(j+1) landed; B(j+2),A(j+2) stay IN FLIGHT across
// the barrier (never drain to 0 mid-loop). Prologue stages tiles 0 and 1; single vmcnt(0)
// at j=NT-2. T2 swizzle for 128B rows: source chunk (l&7)^((l>>3)&7), read (ks*4+g)^(ra&7).
template <bool GELU>
__global__ __launch_bounds__(512, 2) void k_gemm8(const unsigned short* __restrict__ A,
                                                  const unsigned short* __restrict__ Bt,
                                                  const float* __restrict__ bias,
                                                  unsigned short* __restrict__ C,
                                                  int M, int N, int K) {
  __shared__ unsigned short As[2][256 * 64];
  __shared__ unsigned short Bs[2][256 * 64];
  const int rowA0 = blockIdx.y * 256, colB0 = blockIdx.x * 256;
  const int t = threadIdx.x, w = t >> 6, lane = t & 63;
  const int wm = w >> 2, wn = w & 3;
  const int g = lane >> 4, ra = lane & 15;
  const int koff0 = (((0 * 4 + g) ^ (ra & 7)) * 8);
  const int koff1 = (((1 * 4 + g) ^ (ra & 7)) * 8);
  const int srow = w * 8 + (lane >> 3);
  const int schunk = ((lane & 7) ^ ((lane >> 3) & 7)) * 8;

  f32x4 acc[8][4] = {};

  auto stageA = [&](int buf, int kk) {
#pragma unroll
    for (int gq = 0; gq < 4; gq++)
      gl2lds16(A + (size_t)(rowA0 + gq * 64 + srow) * K + kk + schunk,
               &As[buf][gq * 4096 + w * 512]);
  };
  auto stageB = [&](int buf, int kk) {
#pragma unroll
    for (int gq = 0; gq < 4; gq++)
      gl2lds16(Bt + (size_t)(colB0 + gq * 64 + srow) * K + kk + schunk,
               &Bs[buf][gq * 4096 + w * 512]);
  };

  const int NT = K >> 6;
  // prologue: stage tiles 0 and 1; wait only for tile 0 (tile 1's 8 loads stay in flight)
  stageA(0, 0); stageB(0, 0);
  if (NT > 1) { stageA(1, 64); stageB(1, 64); }
  if (NT > 1) asm volatile("s_waitcnt vmcnt(8)" ::: "memory");
  else        asm volatile("s_waitcnt vmcnt(0)" ::: "memory");
  __builtin_amdgcn_sched_barrier(0);
  __builtin_amdgcn_s_barrier();

  bf16x8 aH[4][2], bH[2][2][2];
  const int arow0 = wm * 128, brow0 = wn * 64;
  for (int j = 0; j < NT; ++j) {
    const int buf = j & 1;
    const unsigned short* Ab = &As[buf][0];
    const unsigned short* Bb = &Bs[buf][0];
    // ---------- phase 0: read A-half0 + B-half0; MFMA quad(0,0)
#pragma unroll
    for (int fr = 0; fr < 4; fr++) {
      aH[fr][0] = *(const bf16x8*)&Ab[(arow0 + fr * 16 + ra) * 64 + koff0];
      aH[fr][1] = *(const bf16x8*)&Ab[(arow0 + fr * 16 + ra) * 64 + koff1];
    }
#pragma unroll
    for (int fc = 0; fc < 2; fc++) {
      bH[0][fc][0] = *(const bf16x8*)&Bb[(brow0 + fc * 16 + ra) * 64 + koff0];
      bH[0][fc][1] = *(const bf16x8*)&Bb[(brow0 + fc * 16 + ra) * 64 + koff1];
    }
    __builtin_amdgcn_sched_barrier(0);
    __builtin_amdgcn_s_barrier();
    __builtin_amdgcn_sched_barrier(0);
    __builtin_amdgcn_s_setprio(1);
#pragma unroll
    for (int fr = 0; fr < 4; fr++)
#pragma unroll
      for (int fc = 0; fc < 2; fc++)
#pragma unroll
        for (int ks = 0; ks < 2; ks++)
          acc[fr][fc] = __builtin_amdgcn_mfma_f32_16x16x32_bf16(aH[fr][ks], bH[0][fc][ks], acc[fr][fc], 0, 0, 0);
    __builtin_amdgcn_s_setprio(0);
    __builtin_amdgcn_sched_barrier(0);
    __builtin_amdgcn_s_barrier();
    // ---------- phase 1: read B-half1; MFMA quad(0,1)
#pragma unroll
    for (int fc = 0; fc < 2; fc++) {
      bH[1][fc][0] = *(const bf16x8*)&Bb[(brow0 + 32 + fc * 16 + ra) * 64 + koff0];
      bH[1][fc][1] = *(const bf16x8*)&Bb[(brow0 + 32 + fc * 16 + ra) * 64 + koff1];
    }
    __builtin_amdgcn_sched_barrier(0);
    __builtin_amdgcn_s_barrier();
    __builtin_amdgcn_sched_barrier(0);
    __builtin_amdgcn_s_setprio(1);
#pragma unroll
    for (int fr = 0; fr < 4; fr++)
#pragma unroll
      for (int fc = 0; fc < 2; fc++)
#pragma unroll
        for (int ks = 0; ks < 2; ks++)
          acc[fr][2 + fc] = __builtin_amdgcn_mfma_f32_16x16x32_bf16(aH[fr][ks], bH[1][fc][ks], acc[fr][2 + fc], 0, 0, 0);
    __builtin_amdgcn_s_setprio(0);
    __builtin_amdgcn_sched_barrier(0);
    __builtin_amdgcn_s_barrier();
    // ---------- phase 2: read A-half1; stage B(j+2) into SAME buf (B(j) reads done); MFMA quad(1,0)
#pragma unroll
    for (int fr = 0; fr < 4; fr++) {
      aH[fr][0] = *(const bf16x8*)&Ab[(arow0 + 64 + fr * 16 + ra) * 64 + koff0];
      aH[fr][1] = *(const bf16x8*)&Ab[(arow0 + 64 + fr * 16 + ra) * 64 + koff1];
    }
    if (j + 2 < NT) stageB(buf, (j + 2) << 6);
    __builtin_amdgcn_sched_barrier(0);
    __builtin_amdgcn_s_barrier();
    __builtin_amdgcn_sched_barrier(0);
    __builtin_amdgcn_s_setprio(1);
#pragma unroll
    for (int fr = 0; fr < 4; fr++)
#pragma unroll
      for (int fc = 0; fc < 2; fc++)
#pragma unroll
        for (int ks = 0; ks < 2; ks++)
          acc[4 + fr][fc] = __builtin_amdgcn_mfma_f32_16x16x32_bf16(aH[fr][ks], bH[0][fc][ks], acc[4 + fr][fc], 0, 0, 0);
    __builtin_amdgcn_s_setprio(0);
    __builtin_amdgcn_sched_barrier(0);
    __builtin_amdgcn_s_barrier();
    // ---------- phase 3: stage A(j+2) (A(j) reads done); MFMA quad(1,1); counted boundary
    if (j + 2 < NT) stageA(buf, (j + 2) << 6);
    __builtin_amdgcn_sched_barrier(0);
    __builtin_amdgcn_s_setprio(1);
#pragma unroll
    for (int fr = 0; fr < 4; fr++)
#pragma unroll
      for (int fc = 0; fc < 2; fc++)
#pragma unroll
        for (int ks = 0; ks < 2; ks++)
          acc[4 + fr][2 + fc] = __builtin_amdgcn_mfma_f32_16x16x32_bf16(aH[fr][ks], bH[1][fc][ks], acc[4 + fr][2 + fc], 0, 0, 0);
    __builtin_amdgcn_s_setprio(0);
    if (j + 1 < NT) {
      if (j + 2 < NT) asm volatile("s_waitcnt vmcnt(8)" ::: "memory");  // j+2 loads stay in flight
      else            asm volatile("s_waitcnt vmcnt(0)" ::: "memory");  // once, at j=NT-2
    }
    __builtin_amdgcn_sched_barrier(0);
    __builtin_amdgcn_s_barrier();
  }
  asm volatile("s_waitcnt vmcnt(0) lgkmcnt(0)" ::: "memory");
  __builtin_amdgcn_s_barrier();

  // ---- epilogue: per-wave LDS transpose (XOR-swizzled), 16B coalesced stores ----
  unsigned short* Ep = &As[0][0] + w * 1024;  // 16x64 u16 per wave; no pending writes here
  const int grow0 = rowA0 + wm * 128;
  const int gcol0 = colB0 + wn * 64;
  float bv[4];
#pragma unroll
  for (int n = 0; n < 4; n++) bv[n] = bias ? bias[gcol0 + n * 16 + ra] : 0.f;
  const int rdrow = lane >> 3, rg = lane & 7;
#pragma unroll
  for (int m = 0; m < 8; m++) {
#pragma unroll
    for (int n = 0; n < 4; n++)
#pragma unroll
      for (int i = 0; i < 4; i++) {
        int r = g * 4 + i;
        float v = acc[m][n][i] + bv[n];
        if (GELU) v = 0.5f * v * (1.f + erff(v * 0.70710678118654752f));
        Ep[r * 64 + ((ra + n * 16) ^ ((r & 7) << 3))] = f2bf(v);
      }
    asm volatile("s_waitcnt lgkmcnt(0)" ::: "memory");
    __builtin_amdgcn_sched_barrier(0);
#pragma unroll
    for (int p = 0; p < 2; p++) {
      int rr = p * 8 + rdrow;
      bf16x8 val = *(const bf16x8*)&Ep[rr * 64 + ((rg ^ (rr & 7)) << 3)];
      *(bf16x8*)&C[(size_t)(grow0 + m * 16 + rr) * N + gcol0 + rg * 8] = val;
    }
    asm volatile("s_waitcnt lgkmcnt(0)" ::: "memory");
  }
}

// ======== small MFMA GEMM (folds, 1024^3): 128^2 tile, ring-3 ========
__global__ __launch_bounds__(256) void k_gemmS(const unsigned short* __restrict__ A,
                                               const unsigned short* __restrict__ Bt,
                                               const float* __restrict__ bias,
                                               unsigned short* __restrict__ C,
                                               int M, int N, int K) {
  __shared__ unsigned short As[3][128 * 32];
  __shared__ unsigned short Bs[3][128 * 32];
  const int rowA0 = blockIdx.y * 128, colB0 = blockIdx.x * 128;
  const int t = threadIdx.x, w = t >> 6, lane = t & 63;
  const int wr = w >> 1, wc = w & 1;
  const int srow = w * 16 + (lane >> 2);
  const int schunk = (lane & 3) ^ ((lane >> 3) & 3);
  const unsigned short* pa = A + (size_t)(rowA0 + srow) * K + schunk * 8;
  const unsigned short* pb = Bt + (size_t)(colB0 + srow) * K + schunk * 8;
  const size_t row64 = (size_t)64 * K;
  f32x4 acc[4][4] = {};
  const int g = lane >> 4, ra = lane & 15;
  const int gp8 = (g ^ ((ra >> 1) & 3)) * 8;
  auto stage = [&](int buf, int kk) {
    gl2lds16(pa + kk, &As[buf][w * 512]);
    gl2lds16(pa + row64 + kk, &As[buf][2048 + w * 512]);
    gl2lds16(pb + kk, &Bs[buf][w * 512]);
    gl2lds16(pb + row64 + kk, &Bs[buf][2048 + w * 512]);
  };
  const int NT = K >> 5;
  stage(0, 0);
  if (NT > 1) stage(1, 32);
  int cur = 0;
  for (int j = 0; j < NT; ++j) {
    if (j + 1 < NT) asm volatile("s_waitcnt vmcnt(4)" ::: "memory");
    else            asm volatile("s_waitcnt vmcnt(0)" ::: "memory");
    __syncthreads();
    if (j + 2 < NT) { int nb = cur + 2; if (nb >= 3) nb -= 3; stage(nb, (j + 2) * 32); }
    bf16x8 af[4], bfr[4];
#pragma unroll
    for (int m = 0; m < 4; m++)
      af[m] = *(const bf16x8*)&As[cur][(wr * 64 + m * 16 + ra) * 32 + gp8];
#pragma unroll
    for (int n = 0; n < 4; n++)
      bfr[n] = *(const bf16x8*)&Bs[cur][(wc * 64 + n * 16 + ra) * 32 + gp8];
#pragma unroll
    for (int m = 0; m < 4; m++)
#pragma unroll
      for (int n = 0; n < 4; n++)
        acc[m][n] = __builtin_amdgcn_mfma_f32_16x16x32_bf16(af[m], bfr[n], acc[m][n], 0, 0, 0);
    __syncthreads();
    cur += 1; if (cur >= 3) cur -= 3;
  }
  const int cr = g * 4, cc = ra;
#pragma unroll
  for (int m = 0; m < 4; m++) {
    int grow = rowA0 + wr * 64 + m * 16 + cr;
#pragma unroll
    for (int n = 0; n < 4; n++) {
      int gcol = colB0 + wc * 64 + n * 16 + cc;
      float bvv = bias ? bias[gcol] : 0.f;
#pragma unroll
      for (int i = 0; i < 4; i++)
        C[(size_t)(grow + i) * N + gcol] = f2bf(acc[m][n][i] + bvv);
    }
  }
}

// ---------------- small GEMM (M<=10): C[Mr][1024] = A[Mr][1024] * Wt^T + bias ----------------
__global__ __launch_bounds__(256) void k_gemm10(const unsigned short* __restrict__ A,
                                                const unsigned short* __restrict__ Bt,
                                                const float* __restrict__ bias,
                                                unsigned short* __restrict__ C) {
  __shared__ float af[1024];
  int m = blockIdx.x, nb = blockIdx.y;
  int t = threadIdx.x;
#pragma unroll
  for (int i = 0; i < 4; i++) af[t * 4 + i] = bf2f(A[(size_t)m * 1024 + t * 4 + i]);
  __syncthreads();
  int w = t >> 6, lane = t & 63;
  for (int n = nb * 64 + w; n < nb * 64 + 64; n += 4) {
    const unsigned short* brow = Bt + (size_t)n * 1024 + lane * 16;
    float acc = 0.f;
#pragma unroll
    for (int j = 0; j < 16; j++) acc += af[lane * 16 + j] * bf2f(brow[j]);
#pragma unroll
    for (int o = 32; o; o >>= 1) acc += __shfl_xor(acc, o);
    if (lane == 0) C[(size_t)m * 1024 + n] = f2bf(acc + bias[n]);
  }
}

// ---------------- entmax-1.5 attention, MFMA version (RS = input row stride) ----------------
template <int L, int S, bool SHARED>
__global__ __launch_bounds__(256) void k_attn(const unsigned short* __restrict__ Q,
                                              const unsigned short* __restrict__ Kb,
                                              const unsigned short* __restrict__ Vb,
                                              unsigned short* __restrict__ Out, int RS) {
  constexpr int SP = (S <= 32) ? 32 : 64;
  constexpr int QST = 72;
  constexpr int VST = SP + 8;
  constexpr int CST = SP + 4;
  __shared__ unsigned short Qs[L * QST];
  __shared__ unsigned short Ks[SP * QST];
  __shared__ unsigned short Vt[64 * VST];
  __shared__ float Sc[L * CST];
  __shared__ float Rps[L];
  const int blk = blockIdx.x, batch = blk >> 4, h = blk & 15;
  const int t = threadIdx.x, w = t >> 6, lane = t & 63;
  for (int c = t; c < L * 8; c += 256) {
    int r = c >> 3, ch = (c & 7) * 8;
    *(i32x4*)&Qs[r * QST + ch] =
        *(const i32x4*)&Q[((size_t)(batch * L + r)) * RS + h * 64 + ch];
  }
  for (int c = t; c < SP * 8; c += 256) {
    int r = c >> 3, ch = (c & 7) * 8;
    i32x4 v = {0, 0, 0, 0};
    if (r < S) {
      size_t rb = SHARED ? (size_t)r : (size_t)(batch * S + r);
      v = *(const i32x4*)&Kb[rb * RS + h * 64 + ch];
    }
    *(i32x4*)&Ks[r * QST + ch] = v;
  }
  for (int c = t; c < SP * 64; c += 256) {
    int s = c >> 6, e = c & 63;
    unsigned short v = 0;
    if (s < S) {
      size_t rb = SHARED ? (size_t)s : (size_t)(batch * S + s);
      v = Vb[rb * RS + h * 64 + e];
    }
    Vt[e * VST + s] = v;
  }
  __syncthreads();
  const int ka = (lane >> 4) * 8, ra = lane & 15;
  const int cr = (lane >> 4) * 4, cc = lane & 15;
  constexpr int NT = SP / 16, TT = (L / 16) * NT;
  for (int tt = w; tt < TT; tt += 4) {
    int m = tt / NT, n = tt % NT;
    f32x4 a = {0.f, 0.f, 0.f, 0.f};
#pragma unroll
    for (int ks = 0; ks < 2; ks++) {
      bf16x8 af = *(const bf16x8*)&Qs[(m * 16 + ra) * QST + ks * 32 + ka];
      bf16x8 bf = *(const bf16x8*)&Ks[(n * 16 + ra) * QST + ks * 32 + ka];
      a = __builtin_amdgcn_mfma_f32_16x16x32_bf16(af, bf, a, 0, 0, 0);
    }
#pragma unroll
    for (int i = 0; i < 4; i++)
      Sc[(m * 16 + cr + i) * CST + n * 16 + cc] = a[i] * 0.0625f;
  }
  __syncthreads();
  constexpr int G = 256 / L, RW = 64 / G, SL = SP / G;
  const int row = w * RW + lane / G, sub = lane % G;
  float xs[SL];
#pragma unroll
  for (int j = 0; j < SL; j++) {
    int s = sub * SL + j;
    float v = Sc[row * CST + s];
    if (S < SP && s >= S) v = -1e30f;
    xs[j] = v;
  }
  float mx = xs[0];
#pragma unroll
  for (int j = 1; j < SL; j++) mx = fmaxf(mx, xs[j]);
#pragma unroll
  for (int o = G / 2; o; o >>= 1) mx = fmaxf(mx, __shfl_xor(mx, o));
  const float hoff = (S == 64) ? 0.125f : (S == 32) ? 0.17677669529663687f : 0.31622776601683794f;
  float lo = mx - 1.f, hi = mx - hoff;
#pragma unroll 1
  for (int it = 0; it < 26; it++) {
    float mid = 0.5f * (lo + hi);
    float f = 0.f;
#pragma unroll
    for (int j = 0; j < SL; j++) { float dd = fmaxf(xs[j] - mid, 0.f); f += dd * dd; }
#pragma unroll
    for (int o = G / 2; o; o >>= 1) f += __shfl_xor(f, o);
    bool gt = f > 1.f;
    lo = gt ? mid : lo;
    hi = gt ? hi : mid;
  }
  float tau = 0.5f * (lo + hi);
  float ps = 0.f;
#pragma unroll
  for (int j = 0; j < SL; j++) { float dd = fmaxf(xs[j] - tau, 0.f); xs[j] = dd * dd; ps += xs[j]; }
#pragma unroll
  for (int o = G / 2; o; o >>= 1) ps += __shfl_xor(ps, o);
  if (sub == 0) Rps[row] = 1.f / ps;
  unsigned short* Pb = Qs;
#pragma unroll
  for (int j = 0; j < SL; j += 4) {
    u16x4 pv;
#pragma unroll
    for (int jj = 0; jj < 4; jj++) pv[jj] = f2bf(xs[j + jj]);
    *(u16x4*)&Pb[row * VST + sub * SL + j] = pv;
  }
  __syncthreads();
  constexpr int TT2 = (L / 16) * 4;
  for (int tt = w; tt < TT2; tt += 4) {
    int m = tt >> 2, n = tt & 3;
    f32x4 a = {0.f, 0.f, 0.f, 0.f};
#pragma unroll
    for (int ks = 0; ks < SP / 32; ks++) {
      bf16x8 af = *(const bf16x8*)&Pb[(m * 16 + ra) * VST + ks * 32 + ka];
      bf16x8 bf = *(const bf16x8*)&Vt[(n * 16 + ra) * VST + ks * 32 + ka];
      a = __builtin_amdgcn_mfma_f32_16x16x32_bf16(af, bf, a, 0, 0, 0);
    }
#pragma unroll
    for (int i = 0; i < 4; i++) {
      int l = m * 16 + cr + i, e = n * 16 + cc;
      float val = a[i] * Rps[l];
      int l_new = h * (L / 16) + (l >> 4);
      int cg = (l & 15) * 64 + e;
      Out[((size_t)(batch * L + l_new)) * 1024 + cg] = f2bf(val);
    }
  }
}

// ---------------- LayerNorm(a+b) * g + be, optional row permutation / f32 out ----------------
template <int MODE, bool F32OUT>
__global__ __launch_bounds__(256) void k_ln(const unsigned short* __restrict__ a,
                                            const unsigned short* __restrict__ b,
                                            const float* __restrict__ g,
                                            const float* __restrict__ be,
                                            void* __restrict__ outp) {
  __shared__ float red[8];
  int r = blockIdx.x, t = threadIdx.x;
  size_t base = (size_t)r * 1024 + t * 4;
  u16x4 av = *(const u16x4*)(a + base);
  u16x4 bv = *(const u16x4*)(b + base);
  float x[4];
  float s = 0.f, ss = 0.f;
#pragma unroll
  for (int i = 0; i < 4; i++) {
    x[i] = bf2f(av[i]) + bf2f(bv[i]);
    s += x[i]; ss += x[i] * x[i];
  }
#pragma unroll
  for (int o = 32; o; o >>= 1) { s += __shfl_xor(s, o); ss += __shfl_xor(ss, o); }
  int w = t >> 6;
  if ((t & 63) == 0) { red[w] = s; red[4 + w] = ss; }
  __syncthreads();
  s = red[0] + red[1] + red[2] + red[3];
  ss = red[4] + red[5] + red[6] + red[7];
  float mean = s * (1.f / 1024.f);
  float var = ss * (1.f / 1024.f) - mean * mean;
  float rstd = rsqrtf(var + 1e-5f);
  int orow;
  if (MODE == 0) orow = r;
  else if (MODE == 1) { int bi = r >> 11, rem = r & 2047; int tt = rem >> 6, sd = rem & 63; orow = (bi << 11) + sd * 32 + tt; }
  else { int bi = r >> 11, rem = r & 2047; int sd = rem >> 5, tt = rem & 31; orow = (bi << 11) + tt * 64 + sd; }
  size_t ob = (size_t)orow * 1024 + t * 4;
  if (F32OUT) {
    f32x4 y;
#pragma unroll
    for (int i = 0; i < 4; i++) y[i] = (x[i] - mean) * rstd * g[t * 4 + i] + be[t * 4 + i];
    *(f32x4*)((float*)outp + ob) = y;
  } else {
    u16x4 y;
#pragma unroll
    for (int i = 0; i < 4; i++) y[i] = f2bf((x[i] - mean) * rstd * g[t * 4 + i] + be[t * 4 + i]);
    *(u16x4*)((unsigned short*)outp + ob) = y;
  }
}

// =======================================================================================

extern "C" void kernel_launch(void* const* d_in, const int* in_sizes, int n_in,
                              void* d_out, int out_size, void* d_ws, size_t ws_size,
                              hipStream_t stream) {
  const int M = 16384;
  if (n_in < 43 || in_sizes[0] != 16777216 || in_sizes[25] != 10240 || in_sizes[34] != 4194304) {
    fprintf(stderr, "kernel_launch: unexpected input layout (n_in=%d)\n", n_in);
    return;
  }
  const float* x = (const float*)d_in[0];
  const float* w[3][4]; const float* bia[3][4];
  for (int p = 0; p < 3; p++) {
    w[p][0] = (const float*)d_in[1 + 8 * p + 0]; bia[p][0] = (const float*)d_in[1 + 8 * p + 1];
    w[p][1] = (const float*)d_in[1 + 8 * p + 2]; bia[p][1] = (const float*)d_in[1 + 8 * p + 3];
    w[p][2] = (const float*)d_in[1 + 8 * p + 4]; bia[p][2] = (const float*)d_in[1 + 8 * p + 5];
    w[p][3] = (const float*)d_in[1 + 8 * p + 6]; bia[p][3] = (const float*)d_in[1 + 8 * p + 7];
  }
  const float* cs_key = (const float*)d_in[25];
  const float* ng[4]; const float* nb[4];
  for (int i = 0; i < 4; i++) { ng[i] = (const float*)d_in[26 + 2 * i]; nb[i] = (const float*)d_in[27 + 2 * i]; }
  const float* m_w1[2]; const float* m_b1[2]; const float* m_w2[2]; const float* m_b2[2];
  for (int i = 0; i < 2; i++) {
    m_w1[i] = (const float*)d_in[34 + 4 * i]; m_b1[i] = (const float*)d_in[35 + 4 * i];
    m_w2[i] = (const float*)d_in[36 + 4 * i]; m_b2[i] = (const float*)d_in[37 + 4 * i];
  }

  // ---- workspace: weights ~56 MiB + 6 x 32 MiB activation slots = ~248 MiB ----
  char* base = (char*)d_ws; size_t off = 0;
  auto alloc = [&](size_t bytes) -> void* {
    off = (off + 255) & ~(size_t)255;
    void* p = base + off; off += bytes; return p;
  };
  const size_t W1M = (size_t)1024 * 1024;
  unsigned short* W3ct = (unsigned short*)alloc(3 * W1M * 2);  // [wqT; wkT; wkvT]
  unsigned short* W3hp = (unsigned short*)alloc(3 * W1M * 2);
  unsigned short* Woct = (unsigned short*)alloc(W1M * 2);
  unsigned short* Wohp = (unsigned short*)alloc(W1M * 2);
  unsigned short* Wocs = (unsigned short*)alloc(W1M * 2);
  unsigned short* Wqcs = (unsigned short*)alloc(W1M * 2);
  unsigned short* Wkcs = (unsigned short*)alloc(W1M * 2);
  unsigned short* Wvcs = (unsigned short*)alloc(W1M * 2);
  unsigned short* Wm1u = (unsigned short*)alloc((size_t)4096 * 1024 * 2);
  unsigned short* Wm1d = (unsigned short*)alloc((size_t)1024 * 4096 * 2);
  unsigned short* Wm2u = (unsigned short*)alloc((size_t)4096 * 1024 * 2);
  unsigned short* Wm2d = (unsigned short*)alloc((size_t)1024 * 4096 * 2);
  float* b3ct = (float*)alloc(3072 * 4);
  float* b3hp = (float*)alloc(3072 * 4);
  unsigned short* KeyB = (unsigned short*)alloc((size_t)10 * 1024 * 2);
  unsigned short* Kcs = (unsigned short*)alloc((size_t)10 * 1024 * 2);
  unsigned short* Vcs = (unsigned short*)alloc((size_t)10 * 1024 * 2);
  unsigned short* S[6];
  for (int i = 0; i < 6; i++) S[i] = (unsigned short*)alloc((size_t)M * 1024 * 2);
  if (off > ws_size) {
    fprintf(stderr, "kernel_launch: ws too small: need %zu have %zu\n", off, ws_size);
    return;
  }
  // fold scratch aliased into S1 (dead during prep)
  unsigned short* Wvt_ct = S[1];
  unsigned short* Wraw_ct = S[1] + W1M;
  unsigned short* Wvt_hp = S[1] + 2 * W1M;
  unsigned short* Wraw_hp = S[1] + 3 * W1M;

  auto gemm = [&](const unsigned short* Ap, const unsigned short* Bt, const float* bi,
                  unsigned short* Cp, int Mm, int Nn, int Kk, bool gelu) {
    dim3 gg(Nn / 256, Mm / 256);
    if (gelu) k_gemm8<true><<<gg, 512, 0, stream>>>(Ap, Bt, bi, Cp, Mm, Nn, Kk);
    else      k_gemm8<false><<<gg, 512, 0, stream>>>(Ap, Bt, bi, Cp, Mm, Nn, Kk);
  };
  auto tc = [&](const float* src, unsigned short* dst) {
    k_tcast<<<dim3(32, 32), 256, 0, stream>>>(src, dst, 1024, 1024);
  };

  // ---- weight prep ----
  tc(w[0][0], W3ct); tc(w[0][1], W3ct + W1M);
  tc(w[2][0], W3hp); tc(w[2][1], W3hp + W1M);
  tc(w[0][3], Woct); tc(w[2][3], Wohp); tc(w[1][3], Wocs);
  tc(w[1][0], Wqcs); tc(w[1][1], Wkcs); tc(w[1][2], Wvcs);
  k_tcast<<<dim3(128, 32), 256, 0, stream>>>(m_w1[0], Wm1u, 1024, 4096);
  k_tcast<<<dim3(32, 128), 256, 0, stream>>>(m_w2[0], Wm1d, 4096, 1024);
  k_tcast<<<dim3(128, 32), 256, 0, stream>>>(m_w1[1], Wm2u, 1024, 4096);
  k_tcast<<<dim3(32, 128), 256, 0, stream>>>(m_w2[1], Wm2d, 4096, 1024);
  tc(w[0][2], Wvt_ct); k_cast<<<1024, 256, 0, stream>>>(w[0][1], Wraw_ct, 262144);
  tc(w[2][2], Wvt_hp); k_cast<<<1024, 256, 0, stream>>>(w[2][1], Wraw_hp, 262144);
  k_cast<<<16384, 256, 0, stream>>>(x, S[0], 16777216 / 4);
  k_cast<<<10, 256, 0, stream>>>(cs_key, KeyB, 10240 / 4);
  // folded V weights (1024^3 via the small-tile kernel)
  k_gemmS<<<dim3(8, 8), 256, 0, stream>>>(Wvt_ct, Wraw_ct, nullptr, W3ct + 2 * W1M, 1024, 1024, 1024);
  k_gemmS<<<dim3(8, 8), 256, 0, stream>>>(Wvt_hp, Wraw_hp, nullptr, W3hp + 2 * W1M, 1024, 1024, 1024);
  // folded biases
  k_cpb<<<4, 256, 0, stream>>>(bia[0][0], bia[0][1], b3ct);
  k_bfold<<<4, 256, 0, stream>>>(bia[0][1], w[0][2], bia[0][2], b3ct + 2048);
  k_cpb<<<4, 256, 0, stream>>>(bia[2][0], bia[2][1], b3hp);
  k_bfold<<<4, 256, 0, stream>>>(bia[2][1], w[2][2], bia[2][2], b3hp + 2048);
  k_gemm10<<<dim3(10, 16), 256, 0, stream>>>(KeyB, Wkcs, bia[1][1], Kcs);
  k_gemm10<<<dim3(10, 16), 256, 0, stream>>>(Kcs, Wvcs, bia[1][2], Vcs);

  // ---- stage T (L=S=64 attention over seg) ----
  gemm(S[0], W3ct, b3ct, S[1], M, 3072, 1024, false);                       // QKV -> S1..S3
  k_attn<64, 64, false><<<256 * 16, 256, 0, stream>>>(S[1], S[1] + 1024, S[1] + 2048, S[4], 3072);
  gemm(S[4], Woct, bia[0][3], S[5], M, 1024, 1024, false);                  // enc -> S5
  k_ln<0, false><<<M, 256, 0, stream>>>(S[0], S[5], ng[0], nb[0], S[1]);    // D -> S1
  gemm(S[1], Wm1u, m_b1[0], S[2], M, 4096, 1024, true);                     // H -> S2..S5
  gemm(S[2], Wm1d, m_b2[0], S[0], M, 1024, 4096, false);                    // R -> S0
  k_ln<1, false><<<M, 256, 0, stream>>>(S[1], S[0], ng[1], nb[1], S[2]);    // S_in -> S2 (permuted)

  // ---- stage S (L=32) ----
  gemm(S[2], W3hp, b3hp, S[3], M, 3072, 1024, false);                       // QKVhp -> S3..S5
  k_attn<32, 32, false><<<512 * 16, 256, 0, stream>>>(S[3], S[3] + 1024, S[3] + 2048, S[0], 3072);
  gemm(S[0], Wohp, bia[2][3], S[1], M, 1024, 1024, false);                  // PH -> S1
  gemm(S[2], Wqcs, bia[1][0], S[3], M, 1024, 1024, false);                  // Qcs -> S3
  k_attn<32, 10, true><<<512 * 16, 256, 0, stream>>>(S[3], Kcs, Vcs, S[4], 1024);
  gemm(S[4], Wocs, bia[1][3], S[5], M, 1024, 1024, false);                  // SH -> S5
  k_ln<0, false><<<M, 256, 0, stream>>>(S[5], S[1], ng[2], nb[2], S[0]);    // DE -> S0
  gemm(S[0], Wm2u, m_b1[1], S[1], M, 4096, 1024, true);                     // H -> S1..S4
  gemm(S[1], Wm2d, m_b2[1], S[5], M, 1024, 4096, false);                    // R2 -> S5
  k_ln<2, true><<<M, 256, 0, stream>>>(S[0], S[5], ng[3], nb[3], d_out);    // final LN+permute f32
}